// Round 2
// baseline (9993.981 us; speedup 1.0000x reference)
//
#include <hip/hip_runtime.h>
#include <math.h>

typedef unsigned short u16;
typedef short short8 __attribute__((ext_vector_type(8)));
typedef float f32x4 __attribute__((ext_vector_type(4)));

#define NLAYER 4
#define HDIM 1024
#define NHEAD 16
#define NKVH 4
#define FFDIM 2048
#define NEXP 8
#define SEQ 2048
#define NBATCH 2
#define NTOK (NBATCH*SEQ)
#define NPAIR (NTOK*2)
#define RMS_EPS 1e-5f

// ---- 3-term bf16 split: x = b2f(o0)+b2f(o1)+b2f(o2) + O(x*2^-24) ----
__device__ __forceinline__ u16 b16(float x) {
  unsigned u = __builtin_bit_cast(unsigned, x);
  unsigned r = (u + 0x7FFFu + ((u >> 16) & 1u)) >> 16;
  return (u16)r;
}
__device__ __forceinline__ float b2f(u16 b) {
  return __builtin_bit_cast(float, ((unsigned)b) << 16);
}
__device__ __forceinline__ void split3(float x, u16& o0, u16& o1, u16& o2) {
  o0 = b16(x); float r = x - b2f(o0);
  o1 = b16(r); r -= b2f(o1);
  o2 = b16(r);
}
__device__ __forceinline__ float clip100(float v) {
  return fminf(fmaxf(v, -100.f), 100.f);
}

// ---------------- RMSNorm: fp32 -> fp32 ----------------
__global__ __launch_bounds__(256)
void rmsnorm_kernel(const float* __restrict__ x, const float* __restrict__ w,
                    float* __restrict__ out) {
  int t = blockIdx.x, tid = threadIdx.x;
  const float* xr = x + (long)t * HDIM;
  float4 v = *(const float4*)(xr + tid * 4);
  float ss = v.x*v.x + v.y*v.y + v.z*v.z + v.w*v.w;
  #pragma unroll
  for (int m = 32; m; m >>= 1) ss += __shfl_xor(ss, m);
  __shared__ float sb[4];
  if ((tid & 63) == 0) sb[tid >> 6] = ss;
  __syncthreads();
  ss = sb[0] + sb[1] + sb[2] + sb[3];
  float sc = 1.0f / sqrtf(ss * (1.f/HDIM) + RMS_EPS);
  float4 wv = *(const float4*)(w + tid * 4);
  float* op = out + (long)t * HDIM + tid * 4;
  float4 ov;
  ov.x = v.x*sc*wv.x; ov.y = v.y*sc*wv.y; ov.z = v.z*sc*wv.z; ov.w = v.w*sc*wv.w;
  *(float4*)op = ov;
}

// ---------------- split-precision MFMA GEMM (6-pass bf16) -------------------
// A fp32 [rows,K], B fp32 [K,N].  MODE 0: C = acc; MODE 2: C = clip(C+acc);
// MODE 3: C = silu(C)*acc  (up-proj fused with gate in C).
template<int MODE>
__global__ __launch_bounds__(256)
void gemm_kernel(const float* __restrict__ A, const float* __restrict__ B,
                 float* __restrict__ C,
                 const int* __restrict__ gather, const int* __restrict__ offs,
                 int M, int N, int K, long bstride)
{
  __shared__ u16 As[3][128][40];
  __shared__ u16 Bs[3][128][40];
  int rs, re;
  if (offs) { rs = offs[blockIdx.z]; re = offs[blockIdx.z + 1]; }
  else      { rs = 0;               re = M; }
  int p0 = rs + blockIdx.y * 128;
  if (p0 >= re) return;
  int bn0 = blockIdx.x * 128;
  const float* Bp = B + (long)blockIdx.z * bstride;
  int tid = threadIdx.x;
  int wv = tid >> 6, lane = tid & 63;
  int wr = (wv >> 1) * 64, wc = (wv & 1) * 64;
  int lr = lane & 15, lg = lane >> 4;
  f32x4 acc[4][4];
  #pragma unroll
  for (int m = 0; m < 4; m++)
    #pragma unroll
    for (int n = 0; n < 4; n++)
      acc[m][n] = {0.f, 0.f, 0.f, 0.f};
  int ar = tid >> 1, acg = (tid & 1) * 16;
  long arow = -1;
  if (p0 + ar < re) { int pp = p0 + ar; arow = gather ? gather[pp] : pp; }
  int bk = tid >> 3, bcg = (tid & 7) * 16;
  for (int k0 = 0; k0 < K; k0 += 32) {
    // ---- stage A (16 fp32/thread -> 3 bf16 tiles) ----
    float av[16];
    if (arow >= 0) {
      const float* ap = A + arow * (long)K + k0 + acg;
      float4 f0 = *(const float4*)ap;
      float4 f1 = *(const float4*)(ap + 4);
      float4 f2 = *(const float4*)(ap + 8);
      float4 f3 = *(const float4*)(ap + 12);
      av[0]=f0.x; av[1]=f0.y; av[2]=f0.z; av[3]=f0.w;
      av[4]=f1.x; av[5]=f1.y; av[6]=f1.z; av[7]=f1.w;
      av[8]=f2.x; av[9]=f2.y; av[10]=f2.z; av[11]=f2.w;
      av[12]=f3.x; av[13]=f3.y; av[14]=f3.z; av[15]=f3.w;
    } else {
      #pragma unroll
      for (int j = 0; j < 16; j++) av[j] = 0.f;
    }
    short8 s0[3] = {}, s1[3] = {};
    #pragma unroll
    for (int j = 0; j < 8; j++) {
      u16 t0, t1, t2;
      split3(av[j], t0, t1, t2);
      s0[0][j] = (short)t0; s0[1][j] = (short)t1; s0[2][j] = (short)t2;
      split3(av[8 + j], t0, t1, t2);
      s1[0][j] = (short)t0; s1[1][j] = (short)t1; s1[2][j] = (short)t2;
    }
    #pragma unroll
    for (int t = 0; t < 3; t++) {
      *(short8*)&As[t][ar][acg]     = s0[t];
      *(short8*)&As[t][ar][acg + 8] = s1[t];
    }
    // ---- stage B transposed (16 fp32/thread -> 3 bf16 tiles) ----
    {
      const float* bp = Bp + (long)(k0 + bk) * N + bn0 + bcg;
      float4 f0 = *(const float4*)bp;
      float4 f1 = *(const float4*)(bp + 4);
      float4 f2 = *(const float4*)(bp + 8);
      float4 f3 = *(const float4*)(bp + 12);
      float bvv[16] = {f0.x,f0.y,f0.z,f0.w, f1.x,f1.y,f1.z,f1.w,
                       f2.x,f2.y,f2.z,f2.w, f3.x,f3.y,f3.z,f3.w};
      #pragma unroll
      for (int j = 0; j < 16; j++) {
        u16 t0, t1, t2;
        split3(bvv[j], t0, t1, t2);
        Bs[0][bcg + j][bk] = t0;
        Bs[1][bcg + j][bk] = t1;
        Bs[2][bcg + j][bk] = t2;
      }
    }
    __syncthreads();
    short8 af[3][4], bf[3][4];
    #pragma unroll
    for (int t = 0; t < 3; t++) {
      #pragma unroll
      for (int m = 0; m < 4; m++) af[t][m] = *(const short8*)&As[t][wr + m*16 + lr][lg*8];
      #pragma unroll
      for (int n = 0; n < 4; n++) bf[t][n] = *(const short8*)&Bs[t][wc + n*16 + lr][lg*8];
    }
    #pragma unroll
    for (int m = 0; m < 4; m++)
      #pragma unroll
      for (int n = 0; n < 4; n++) {
        f32x4 a = acc[m][n];
        a = __builtin_amdgcn_mfma_f32_16x16x32_bf16(af[0][m], bf[0][n], a, 0, 0, 0);
        a = __builtin_amdgcn_mfma_f32_16x16x32_bf16(af[0][m], bf[1][n], a, 0, 0, 0);
        a = __builtin_amdgcn_mfma_f32_16x16x32_bf16(af[1][m], bf[0][n], a, 0, 0, 0);
        a = __builtin_amdgcn_mfma_f32_16x16x32_bf16(af[1][m], bf[1][n], a, 0, 0, 0);
        a = __builtin_amdgcn_mfma_f32_16x16x32_bf16(af[0][m], bf[2][n], a, 0, 0, 0);
        a = __builtin_amdgcn_mfma_f32_16x16x32_bf16(af[2][m], bf[0][n], a, 0, 0, 0);
        acc[m][n] = a;
      }
    __syncthreads();
  }
  #pragma unroll
  for (int m = 0; m < 4; m++) {
    int row0 = p0 + wr + m*16 + lg*4;
    #pragma unroll
    for (int n = 0; n < 4; n++) {
      int col = bn0 + wc + n*16 + lr;
      #pragma unroll
      for (int r = 0; r < 4; r++) {
        int row = row0 + r;
        if (row < re) {
          float vvv = acc[m][n][r];
          long idx = (long)row * N + col;
          if constexpr (MODE == 0) C[idx] = vvv;
          else if constexpr (MODE == 2) C[idx] = clip100(C[idx] + vvv);
          else {
            float gv = C[idx];
            C[idx] = gv / (1.f + expf(-gv)) * vvv;
          }
        }
      }
    }
  }
}

// ---------------- RoPE cos/sin table (matches np f32 semantics) ----------------
__global__ __launch_bounds__(256)
void rope_table_kernel(float* __restrict__ tab) {
  int idx = blockIdx.x * 256 + threadIdx.x;   // SEQ*32
  int i = idx & 31, pos = idx >> 5;
  double e = -(double)i * 0.28782313662425575;   // ln(10000)/32
  float inv = (float)exp(e);                     // correctly-rounded 10000^(-i/32)
  float f = (float)pos * inv;                    // f32 multiply, as np does
  tab[idx] = cosf(f);
  tab[SEQ*32 + idx] = sinf(f);
}

__global__ __launch_bounds__(256)
void rope_kernel(float* __restrict__ q, float* __restrict__ k,
                 const float* __restrict__ tab) {
  long idx = (long)blockIdx.x * 256 + threadIdx.x;
  if (idx >= (long)NTOK * 20 * 32) return;
  int i  = (int)(idx & 31);
  int hs = (int)((idx >> 5) % 20);       // 0..15 q heads, 16..19 kv heads
  int t  = (int)(idx / (20 * 32));
  int pos = t & (SEQ - 1);
  float c = tab[pos*32 + i];
  float s = tab[SEQ*32 + pos*32 + i];
  float* base = (hs < 16) ? (q + (long)t * 1024 + hs * 64)
                          : (k + (long)t * 256 + (hs - 16) * 64);
  float x0 = base[i], x1 = base[i + 32];
  base[i]      = x0 * c - x1 * s;
  base[i + 32] = x1 * c + x0 * s;
}

// ---------------- causal flash attention, 6-pass split precision ----------------
__global__ __launch_bounds__(256)
void attn_kernel(const float* __restrict__ q, const float* __restrict__ k,
                 const float* __restrict__ v, float* __restrict__ o)
{
  int qt = blockIdx.x;
  int h  = blockIdx.y;
  int b  = blockIdx.z;
  int kvh = h >> 2;
  int tid = threadIdx.x, w = tid >> 6, lane = tid & 63;
  int lr = lane & 15, lg = lane >> 4;
  __shared__ u16 Vt[3][64][72];       // [term][hd][kv]
  __shared__ u16 Ps[3][4][16][72];    // [term][wave][qrow][kv]
  long tokbase = (long)b * SEQ;
  int q0 = qt * 64;
  // Q fragments, 3 split terms x 2 k-halves
  const float* qrow = q + (tokbase + q0 + w*16 + lr) * 1024 + h * 64;
  short8 aq[3][2];
  #pragma unroll
  for (int hf = 0; hf < 2; hf++) {
    float4 f0 = *(const float4*)(qrow + hf*32 + lg*8);
    float4 f1 = *(const float4*)(qrow + hf*32 + lg*8 + 4);
    float qv[8] = {f0.x,f0.y,f0.z,f0.w, f1.x,f1.y,f1.z,f1.w};
    #pragma unroll
    for (int j = 0; j < 8; j++) {
      u16 t0, t1, t2;
      split3(qv[j], t0, t1, t2);
      aq[0][hf][j] = (short)t0; aq[1][hf][j] = (short)t1; aq[2][hf][j] = (short)t2;
    }
  }
  f32x4 Oacc[4];
  #pragma unroll
  for (int n = 0; n < 4; n++) Oacc[n] = {0.f,0.f,0.f,0.f};
  float mrow[4] = {-1e30f,-1e30f,-1e30f,-1e30f};
  float lrow[4] = {0.f,0.f,0.f,0.f};
  for (int kt = 0; kt <= qt; kt++) {
    __syncthreads();
    { // stage V transposed, 3 terms
      int kvr = tid >> 2, cg = (tid & 3) * 16;
      const float* vs = v + (tokbase + kt*64 + kvr) * 256 + kvh * 64 + cg;
      float4 f0 = *(const float4*)vs;
      float4 f1 = *(const float4*)(vs + 4);
      float4 f2 = *(const float4*)(vs + 8);
      float4 f3 = *(const float4*)(vs + 12);
      float vvv[16] = {f0.x,f0.y,f0.z,f0.w, f1.x,f1.y,f1.z,f1.w,
                       f2.x,f2.y,f2.z,f2.w, f3.x,f3.y,f3.z,f3.w};
      #pragma unroll
      for (int j = 0; j < 16; j++) {
        u16 t0, t1, t2;
        split3(vvv[j], t0, t1, t2);
        Vt[0][cg + j][kvr] = t0;
        Vt[1][cg + j][kvr] = t1;
        Vt[2][cg + j][kvr] = t2;
      }
    }
    // S = (Q K^T)/8 -- K rows as B^T fragments, 12 MFMAs per n
    float sv[4][4];
    #pragma unroll
    for (int n = 0; n < 4; n++) {
      const float* krow = k + (tokbase + kt*64 + n*16 + lr) * 256 + kvh * 64;
      short8 bk_[3][2];
      #pragma unroll
      for (int hf = 0; hf < 2; hf++) {
        float4 f0 = *(const float4*)(krow + hf*32 + lg*8);
        float4 f1 = *(const float4*)(krow + hf*32 + lg*8 + 4);
        float kv_[8] = {f0.x,f0.y,f0.z,f0.w, f1.x,f1.y,f1.z,f1.w};
        #pragma unroll
        for (int j = 0; j < 8; j++) {
          u16 t0, t1, t2;
          split3(kv_[j], t0, t1, t2);
          bk_[0][hf][j] = (short)t0; bk_[1][hf][j] = (short)t1; bk_[2][hf][j] = (short)t2;
        }
      }
      f32x4 c = {0.f,0.f,0.f,0.f};
      #pragma unroll
      for (int hf = 0; hf < 2; hf++) {
        c = __builtin_amdgcn_mfma_f32_16x16x32_bf16(aq[0][hf], bk_[0][hf], c, 0, 0, 0);
        c = __builtin_amdgcn_mfma_f32_16x16x32_bf16(aq[0][hf], bk_[1][hf], c, 0, 0, 0);
        c = __builtin_amdgcn_mfma_f32_16x16x32_bf16(aq[1][hf], bk_[0][hf], c, 0, 0, 0);
        c = __builtin_amdgcn_mfma_f32_16x16x32_bf16(aq[1][hf], bk_[1][hf], c, 0, 0, 0);
        c = __builtin_amdgcn_mfma_f32_16x16x32_bf16(aq[0][hf], bk_[2][hf], c, 0, 0, 0);
        c = __builtin_amdgcn_mfma_f32_16x16x32_bf16(aq[2][hf], bk_[0][hf], c, 0, 0, 0);
      }
      #pragma unroll
      for (int r = 0; r < 4; r++) sv[n][r] = c[r] * 0.125f;
    }
    if (kt == qt) {
      #pragma unroll
      for (int n = 0; n < 4; n++)
        #pragma unroll
        for (int r = 0; r < 4; r++)
          if (n*16 + lr > w*16 + lg*4 + r) sv[n][r] = -1e30f;
    }
    float pvv[4][4];
    float alpha[4];
    #pragma unroll
    for (int r = 0; r < 4; r++) {
      float vm = fmaxf(fmaxf(sv[0][r], sv[1][r]), fmaxf(sv[2][r], sv[3][r]));
      #pragma unroll
      for (int msk = 1; msk < 16; msk <<= 1) vm = fmaxf(vm, __shfl_xor(vm, msk));
      float mnew = fmaxf(mrow[r], vm);
      alpha[r] = expf(mrow[r] - mnew);
      float psum = 0.f;
      #pragma unroll
      for (int n = 0; n < 4; n++) { pvv[n][r] = expf(sv[n][r] - mnew); psum += pvv[n][r]; }
      #pragma unroll
      for (int msk = 1; msk < 16; msk <<= 1) psum += __shfl_xor(psum, msk);
      lrow[r] = lrow[r] * alpha[r] + psum;
      mrow[r] = mnew;
    }
    #pragma unroll
    for (int n = 0; n < 4; n++)
      #pragma unroll
      for (int r = 0; r < 4; r++) {
        u16 t0, t1, t2;
        split3(pvv[n][r], t0, t1, t2);
        Ps[0][w][lg*4 + r][n*16 + lr] = t0;
        Ps[1][w][lg*4 + r][n*16 + lr] = t1;
        Ps[2][w][lg*4 + r][n*16 + lr] = t2;
      }
    #pragma unroll
    for (int n = 0; n < 4; n++)
      #pragma unroll
      for (int r = 0; r < 4; r++) Oacc[n][r] *= alpha[r];
    __syncthreads();
    // O += P V, 6 passes
    #pragma unroll
    for (int kk = 0; kk < 2; kk++) {
      short8 ap0 = *(const short8*)&Ps[0][w][lr][kk*32 + lg*8];
      short8 ap1 = *(const short8*)&Ps[1][w][lr][kk*32 + lg*8];
      short8 ap2 = *(const short8*)&Ps[2][w][lr][kk*32 + lg*8];
      #pragma unroll
      for (int n = 0; n < 4; n++) {
        short8 bv0 = *(const short8*)&Vt[0][n*16 + lr][kk*32 + lg*8];
        short8 bv1 = *(const short8*)&Vt[1][n*16 + lr][kk*32 + lg*8];
        short8 bv2 = *(const short8*)&Vt[2][n*16 + lr][kk*32 + lg*8];
        f32x4 a = Oacc[n];
        a = __builtin_amdgcn_mfma_f32_16x16x32_bf16(ap0, bv0, a, 0, 0, 0);
        a = __builtin_amdgcn_mfma_f32_16x16x32_bf16(ap0, bv1, a, 0, 0, 0);
        a = __builtin_amdgcn_mfma_f32_16x16x32_bf16(ap1, bv0, a, 0, 0, 0);
        a = __builtin_amdgcn_mfma_f32_16x16x32_bf16(ap1, bv1, a, 0, 0, 0);
        a = __builtin_amdgcn_mfma_f32_16x16x32_bf16(ap0, bv2, a, 0, 0, 0);
        a = __builtin_amdgcn_mfma_f32_16x16x32_bf16(ap2, bv0, a, 0, 0, 0);
        Oacc[n] = a;
      }
    }
  }
  float* orow = o + (tokbase + q0 + w*16) * 1024 + h * 64;
  #pragma unroll
  for (int n = 0; n < 4; n++)
    #pragma unroll
    for (int r = 0; r < 4; r++)
      orow[(lg*4 + r) * 1024 + n*16 + lr] = Oacc[n][r] / lrow[r];
}

// ---------------- router (pure fp32) ----------------
__global__ __launch_bounds__(64)
void router_kernel(const float* __restrict__ x, const float* __restrict__ w2,
                   const float* __restrict__ wr, int* __restrict__ tok_e,
                   float* __restrict__ tok_w, int* __restrict__ counts)
{
  int t = blockIdx.x, l = threadIdx.x;
  const float* xr = x + (long)t * HDIM;
  float xv[16];
  float ss = 0.f;
  #pragma unroll
  for (int j = 0; j < 16; j++) { xv[j] = xr[l + j*64]; ss += xv[j]*xv[j]; }
  #pragma unroll
  for (int m = 32; m; m >>= 1) ss += __shfl_xor(ss, m);
  float sc = 1.0f / sqrtf(ss * (1.f/HDIM) + RMS_EPS);
  float acc[8] = {0,0,0,0,0,0,0,0};
  #pragma unroll
  for (int j = 0; j < 16; j++) {
    int hh = l + j*64;
    float xnv = xv[j] * sc * w2[hh];
    const float* wrow = wr + hh * 8;
    #pragma unroll
    for (int e = 0; e < 8; e++) acc[e] += xnv * wrow[e];
  }
  #pragma unroll
  for (int e = 0; e < 8; e++)
    #pragma unroll
    for (int m = 32; m; m >>= 1) acc[e] += __shfl_xor(acc[e], m);
  if (l == 0) {
    float mx = acc[0];
    #pragma unroll
    for (int e = 1; e < 8; e++) mx = fmaxf(mx, acc[e]);
    float ex[8], s = 0.f;
    #pragma unroll
    for (int e = 0; e < 8; e++) { ex[e] = expf(acc[e] - mx); s += ex[e]; }
    int e0 = 0;
    #pragma unroll
    for (int e = 1; e < 8; e++) if (ex[e] > ex[e0]) e0 = e;
    int e1 = (e0 == 0) ? 1 : 0;
    for (int e = 0; e < 8; e++) if (e != e0 && ex[e] > ex[e1]) e1 = e;
    float v0 = ex[e0] / s, v1 = ex[e1] / s, wsum = v0 + v1;
    tok_e[2*t] = e0; tok_e[2*t+1] = e1;
    tok_w[2*t] = v0 / wsum; tok_w[2*t+1] = v1 / wsum;
    atomicAdd(&counts[e0], 1);
    atomicAdd(&counts[e1], 1);
  }
}

__global__ void scan_kernel(const int* __restrict__ counts, int* __restrict__ offs,
                            int* __restrict__ cursor) {
  if (threadIdx.x == 0 && blockIdx.x == 0) {
    int s = 0;
    for (int e = 0; e < NEXP; e++) { offs[e] = s; cursor[e] = s; s += counts[e]; }
    offs[NEXP] = s;
  }
}

__global__ __launch_bounds__(256)
void scatter_kernel(const int* __restrict__ tok_e, int* __restrict__ cursor,
                    int* __restrict__ tok_of_pair, int* __restrict__ tok_slot) {
  int t = blockIdx.x * 256 + threadIdx.x;
  if (t >= NTOK) return;
  #pragma unroll
  for (int s = 0; s < 2; s++) {
    int e = tok_e[2*t + s];
    int pos = atomicAdd(&cursor[e], 1);
    tok_of_pair[pos] = t;
    tok_slot[2*t + s] = pos;
  }
}

// x = clip(x + w0*po[s0] + w1*po[s1])
__global__ __launch_bounds__(256)
void combine_kernel(float* __restrict__ x, const float* __restrict__ po,
                    const int* __restrict__ tok_slot, const float* __restrict__ tok_w) {
  int t = blockIdx.x, tid = threadIdx.x;
  long s0 = tok_slot[2*t], s1 = tok_slot[2*t+1];
  float w0 = tok_w[2*t], w1 = tok_w[2*t+1];
  int c = tid * 4;
  float4 xv = *(float4*)(x + (long)t*HDIM + c);
  float4 a  = *(const float4*)(po + s0*HDIM + c);
  float4 bb = *(const float4*)(po + s1*HDIM + c);
  xv.x = clip100(xv.x + w0*a.x + w1*bb.x);
  xv.y = clip100(xv.y + w0*a.y + w1*bb.y);
  xv.z = clip100(xv.z + w0*a.z + w1*bb.z);
  xv.w = clip100(xv.w + w0*a.w + w1*bb.w);
  *(float4*)(x + (long)t*HDIM + c) = xv;
}

extern "C" void kernel_launch(void* const* d_in, const int* in_sizes, int n_in,
                              void* d_out, int out_size, void* d_ws, size_t ws_size,
                              hipStream_t stream)
{
  (void)in_sizes; (void)n_in; (void)out_size; (void)ws_size;
  const float* hs  = (const float*)d_in[0];
  const float* ln1 = (const float*)d_in[1];
  const float* ln2 = (const float*)d_in[2];
  const float* wq  = (const float*)d_in[3];
  const float* wk  = (const float*)d_in[4];
  const float* wvv = (const float*)d_in[5];
  const float* wo  = (const float*)d_in[6];
  const float* wr  = (const float*)d_in[7];
  const float* wg  = (const float*)d_in[8];
  const float* wu  = (const float*)d_in[9];
  const float* wd  = (const float*)d_in[10];
  float* x = (float*)d_out;

  char* p = (char*)d_ws;
  auto carve = [&](size_t bytes) {
    char* r = p; p += (bytes + 255) & ~(size_t)255; return r;
  };
  float* tab = (float*)carve((size_t)SEQ * 32 * 2 * 4);
  float* xn  = (float*)carve((size_t)NTOK * HDIM * 4);
  char*  big = carve((size_t)NPAIR * FFDIM * 4);          // 64MB shared region
  float* qb  = (float*)big;                               // attn phase
  float* kb  = (float*)(big + (size_t)NTOK * 1024 * 4);
  float* vb  = (float*)(big + (size_t)NTOK * 1024 * 4 + (size_t)NTOK * 256 * 4);
  float* ao  = (float*)(big + (size_t)NTOK * 1024 * 4 + (size_t)NTOK * 512 * 4);
  float* g   = (float*)big;                               // MoE phase (aliases attn bufs)
  float* po  = (float*)carve((size_t)NPAIR * HDIM * 4);
  int*   tok_e       = (int*)carve(NTOK * 2 * 4);
  float* tok_w       = (float*)carve(NTOK * 2 * 4);
  int*   tok_slot    = (int*)carve(NTOK * 2 * 4);
  int*   tok_of_pair = (int*)carve(NPAIR * 4);
  int*   counts      = (int*)carve(8 * 4);
  int*   offs        = (int*)carve(9 * 4);
  int*   cursor      = (int*)carve(8 * 4);

  hipMemcpyAsync(x, hs, (size_t)NTOK * HDIM * 4, hipMemcpyDeviceToDevice, stream);
  rope_table_kernel<<<SEQ*32/256, 256, 0, stream>>>(tab);

  for (int l = 0; l < NLAYER; l++) {
    rmsnorm_kernel<<<NTOK, 256, 0, stream>>>(x, ln1 + (long)l*HDIM, xn);
    gemm_kernel<0><<<dim3(8, 32, 1), 256, 0, stream>>>(
        xn, wq + (long)l*HDIM*1024, qb, nullptr, nullptr, NTOK, 1024, HDIM, 0);
    gemm_kernel<0><<<dim3(2, 32, 1), 256, 0, stream>>>(
        xn, wk + (long)l*HDIM*256, kb, nullptr, nullptr, NTOK, 256, HDIM, 0);
    gemm_kernel<0><<<dim3(2, 32, 1), 256, 0, stream>>>(
        xn, wvv + (long)l*HDIM*256, vb, nullptr, nullptr, NTOK, 256, HDIM, 0);
    rope_kernel<<<(NTOK*20*32)/256, 256, 0, stream>>>(qb, kb, tab);
    attn_kernel<<<dim3(SEQ/64, NHEAD, NBATCH), 256, 0, stream>>>(qb, kb, vb, ao);
    gemm_kernel<2><<<dim3(8, 32, 1), 256, 0, stream>>>(
        ao, wo + (long)l*1024*HDIM, x, nullptr, nullptr, NTOK, HDIM, 1024, 0);

    rmsnorm_kernel<<<NTOK, 256, 0, stream>>>(x, ln2 + (long)l*HDIM, xn);
    hipMemsetAsync(counts, 0, 8 * 4, stream);
    router_kernel<<<NTOK, 64, 0, stream>>>(
        x, ln2 + (long)l*HDIM, wr + (long)l*HDIM*NEXP, tok_e, tok_w, counts);
    scan_kernel<<<1, 64, 0, stream>>>(counts, offs, cursor);
    scatter_kernel<<<NTOK/256, 256, 0, stream>>>(tok_e, cursor, tok_of_pair, tok_slot);
    gemm_kernel<0><<<dim3(16, 32, 8), 256, 0, stream>>>(
        xn, wg + (long)l*NEXP*HDIM*FFDIM, g, tok_of_pair, offs,
        0, FFDIM, HDIM, (long)HDIM*FFDIM);
    gemm_kernel<3><<<dim3(16, 32, 8), 256, 0, stream>>>(
        xn, wu + (long)l*NEXP*HDIM*FFDIM, g, tok_of_pair, offs,
        0, FFDIM, HDIM, (long)HDIM*FFDIM);
    gemm_kernel<0><<<dim3(8, 32, 8), 256, 0, stream>>>(
        g, wd + (long)l*NEXP*FFDIM*HDIM, po, nullptr, offs,
        0, HDIM, FFDIM, (long)FFDIM*HDIM);
    combine_kernel<<<NTOK, 256, 0, stream>>>(x, po, tok_slot, tok_w);
  }
}

// Round 3
// 6244.691 us; speedup vs baseline: 1.6004x; 1.6004x over previous
//
#include <hip/hip_runtime.h>
#include <math.h>

typedef unsigned short u16;
typedef short short8 __attribute__((ext_vector_type(8)));
typedef short short4v __attribute__((ext_vector_type(4)));
typedef float f32x4 __attribute__((ext_vector_type(4)));

#define NLAYER 4
#define HDIM 1024
#define NHEAD 16
#define NKVH 4
#define FFDIM 2048
#define NEXP 8
#define SEQ 2048
#define NBATCH 2
#define NTOK (NBATCH*SEQ)
#define NPAIR (NTOK*2)
#define RMS_EPS 1e-5f

// ---- 2-term bf16 split: x = b2f(o0)+b2f(o1) + O(x*2^-18) ----
__device__ __forceinline__ u16 b16(float x) {
  unsigned u = __builtin_bit_cast(unsigned, x);
  unsigned r = (u + 0x7FFFu + ((u >> 16) & 1u)) >> 16;
  return (u16)r;
}
__device__ __forceinline__ float b2f(u16 b) {
  return __builtin_bit_cast(float, ((unsigned)b) << 16);
}
__device__ __forceinline__ void split2(float x, u16& o0, u16& o1) {
  o0 = b16(x); o1 = b16(x - b2f(o0));
}
__device__ __forceinline__ float clip100(float v) {
  return fminf(fmaxf(v, -100.f), 100.f);
}

// ---------------- RMSNorm: fp32 -> fp32 ----------------
__global__ __launch_bounds__(256)
void rmsnorm_kernel(const float* __restrict__ x, const float* __restrict__ w,
                    float* __restrict__ out) {
  int t = blockIdx.x, tid = threadIdx.x;
  const float* xr = x + (long)t * HDIM;
  float4 v = *(const float4*)(xr + tid * 4);
  float ss = v.x*v.x + v.y*v.y + v.z*v.z + v.w*v.w;
  #pragma unroll
  for (int m = 32; m; m >>= 1) ss += __shfl_xor(ss, m);
  __shared__ float sb[4];
  if ((tid & 63) == 0) sb[tid >> 6] = ss;
  __syncthreads();
  ss = sb[0] + sb[1] + sb[2] + sb[3];
  float sc = 1.0f / sqrtf(ss * (1.f/HDIM) + RMS_EPS);
  float4 wv = *(const float4*)(w + tid * 4);
  float4 ov;
  ov.x = v.x*sc*wv.x; ov.y = v.y*sc*wv.y; ov.z = v.z*sc*wv.z; ov.w = v.w*sc*wv.w;
  *(float4*)(out + (long)t * HDIM + tid * 4) = ov;
}

// ---------------- split-precision MFMA GEMM (2-term, 3-pass) ----------------
// A fp32 [rows,K], B fp32 [K,N]. MODE 0: C = acc; MODE 2: C = clip(C+acc);
// MODE 3: C = silu(C)*acc.
#define APAD 36
template<int MODE>
__global__ __launch_bounds__(256)
void gemm_kernel(const float* __restrict__ A, const float* __restrict__ B,
                 float* __restrict__ C,
                 const int* __restrict__ gather, const int* __restrict__ offs,
                 int M, int N, int K, long bstride)
{
  __shared__ u16 As[2][128][APAD];
  __shared__ u16 Bs[2][128][APAD];
  int rs, re;
  if (offs) { rs = offs[blockIdx.z]; re = offs[blockIdx.z + 1]; }
  else      { rs = 0;               re = M; }
  int p0 = rs + blockIdx.y * 128;
  if (p0 >= re) return;
  int bn0 = blockIdx.x * 128;
  const float* Bp = B + (long)blockIdx.z * bstride;
  int tid = threadIdx.x;
  int wv = tid >> 6, lane = tid & 63;
  int wr = (wv >> 1) * 64, wc = (wv & 1) * 64;
  int lr = lane & 15, lg = lane >> 4;
  f32x4 acc[4][4];
  #pragma unroll
  for (int m = 0; m < 4; m++)
    #pragma unroll
    for (int n = 0; n < 4; n++)
      acc[m][n] = {0.f, 0.f, 0.f, 0.f};
  // A-stage: thread covers rows a_r0+32j (j=0..3), k-quad a_kq (coalesced rows)
  int a_kq = (tid & 7) * 4;
  int a_r0 = tid >> 3;
  long arow_[4];
  #pragma unroll
  for (int j = 0; j < 4; j++) {
    int rr = p0 + a_r0 + 32*j;
    arow_[j] = (rr < re) ? (long)(gather ? gather[rr] : rr) : -1;
  }
  // B-stage: thread owns column b_col, 16 consecutive k at b_kh
  int b_col = tid & 127;
  int b_kh = (tid >> 7) * 16;
  const float* bp_base = Bp + bn0 + b_col;

  for (int k0 = 0; k0 < K; k0 += 32) {
    // ---- stage A ----
    #pragma unroll
    for (int j = 0; j < 4; j++) {
      float4 f = {0.f,0.f,0.f,0.f};
      if (arow_[j] >= 0) f = *(const float4*)(A + arow_[j]*K + k0 + a_kq);
      u16 h0,l0,h1,l1,h2,l2,h3,l3;
      split2(f.x,h0,l0); split2(f.y,h1,l1); split2(f.z,h2,l2); split2(f.w,h3,l3);
      short4v hv = {(short)h0,(short)h1,(short)h2,(short)h3};
      short4v lv = {(short)l0,(short)l1,(short)l2,(short)l3};
      *(short4v*)&As[0][a_r0 + 32*j][a_kq] = hv;
      *(short4v*)&As[1][a_r0 + 32*j][a_kq] = lv;
    }
    // ---- stage B (coalesced scalar loads, vector LDS writes) ----
    {
      const float* bp = bp_base + (long)(k0 + b_kh) * N;
      short8 hv0, hv1, lv0, lv1;
      #pragma unroll
      for (int j = 0; j < 8; j++) {
        u16 h, l;
        split2(bp[j * N], h, l);
        hv0[j] = (short)h; lv0[j] = (short)l;
      }
      #pragma unroll
      for (int j = 0; j < 8; j++) {
        u16 h, l;
        split2(bp[(j + 8) * N], h, l);
        hv1[j] = (short)h; lv1[j] = (short)l;
      }
      *(short8*)&Bs[0][b_col][b_kh]     = hv0;
      *(short8*)&Bs[0][b_col][b_kh + 8] = hv1;
      *(short8*)&Bs[1][b_col][b_kh]     = lv0;
      *(short8*)&Bs[1][b_col][b_kh + 8] = lv1;
    }
    __syncthreads();
    short8 af[2][4], bf[2][4];
    #pragma unroll
    for (int t = 0; t < 2; t++) {
      #pragma unroll
      for (int m = 0; m < 4; m++) af[t][m] = *(const short8*)&As[t][wr + m*16 + lr][lg*8];
      #pragma unroll
      for (int n = 0; n < 4; n++) bf[t][n] = *(const short8*)&Bs[t][wc + n*16 + lr][lg*8];
    }
    #pragma unroll
    for (int m = 0; m < 4; m++)
      #pragma unroll
      for (int n = 0; n < 4; n++) {
        f32x4 a = acc[m][n];
        a = __builtin_amdgcn_mfma_f32_16x16x32_bf16(af[0][m], bf[0][n], a, 0, 0, 0);
        a = __builtin_amdgcn_mfma_f32_16x16x32_bf16(af[0][m], bf[1][n], a, 0, 0, 0);
        a = __builtin_amdgcn_mfma_f32_16x16x32_bf16(af[1][m], bf[0][n], a, 0, 0, 0);
        acc[m][n] = a;
      }
    __syncthreads();
  }
  #pragma unroll
  for (int m = 0; m < 4; m++) {
    int row0 = p0 + wr + m*16 + lg*4;
    #pragma unroll
    for (int n = 0; n < 4; n++) {
      int col = bn0 + wc + n*16 + lr;
      #pragma unroll
      for (int r = 0; r < 4; r++) {
        int row = row0 + r;
        if (row < re) {
          float vvv = acc[m][n][r];
          long idx = (long)row * N + col;
          if constexpr (MODE == 0) C[idx] = vvv;
          else if constexpr (MODE == 2) C[idx] = clip100(C[idx] + vvv);
          else {
            float gv = C[idx];
            C[idx] = gv / (1.f + expf(-gv)) * vvv;
          }
        }
      }
    }
  }
}

// ---------------- RoPE cos/sin table (matches np f32 semantics) ----------------
__global__ __launch_bounds__(256)
void rope_table_kernel(float* __restrict__ tab) {
  int idx = blockIdx.x * 256 + threadIdx.x;   // SEQ*32
  int i = idx & 31, pos = idx >> 5;
  double e = -(double)i * 0.28782313662425575;   // ln(10000)/32
  float inv = (float)exp(e);
  float f = (float)pos * inv;
  tab[idx] = cosf(f);
  tab[SEQ*32 + idx] = sinf(f);
}

__global__ __launch_bounds__(256)
void rope_kernel(float* __restrict__ q, float* __restrict__ k,
                 const float* __restrict__ tab) {
  long idx = (long)blockIdx.x * 256 + threadIdx.x;
  if (idx >= (long)NTOK * 20 * 32) return;
  int i  = (int)(idx & 31);
  int hs = (int)((idx >> 5) % 20);
  int t  = (int)(idx / (20 * 32));
  int pos = t & (SEQ - 1);
  float c = tab[pos*32 + i];
  float s = tab[SEQ*32 + pos*32 + i];
  float* base = (hs < 16) ? (q + (long)t * 1024 + hs * 64)
                          : (k + (long)t * 256 + (hs - 16) * 64);
  float x0 = base[i], x1 = base[i + 32];
  base[i]      = x0 * c - x1 * s;
  base[i + 32] = x1 * c + x0 * s;
}

// ---------------- causal flash attention, 2-term / 3-pass ----------------
#define VPAD 72
#define PPAD 68
__global__ __launch_bounds__(256)
void attn_kernel(const float* __restrict__ q, const float* __restrict__ k,
                 const float* __restrict__ v, float* __restrict__ o)
{
  int qt = blockIdx.x;
  int h  = blockIdx.y;
  int b  = blockIdx.z;
  int kvh = h >> 2;
  int tid = threadIdx.x, w = tid >> 6, lane = tid & 63;
  int lr = lane & 15, lg = lane >> 4;
  __shared__ u16 Vt[2][64][VPAD];       // [term][hd][kv]
  __shared__ u16 Ps[2][4][16][PPAD];    // [term][wave][qrow][kv]
  long tokbase = (long)b * SEQ;
  int q0 = qt * 64;
  const float* qrow = q + (tokbase + q0 + w*16 + lr) * 1024 + h * 64;
  short8 aq[2][2];
  #pragma unroll
  for (int hf = 0; hf < 2; hf++) {
    float4 f0 = *(const float4*)(qrow + hf*32 + lg*8);
    float4 f1 = *(const float4*)(qrow + hf*32 + lg*8 + 4);
    float qv[8] = {f0.x,f0.y,f0.z,f0.w, f1.x,f1.y,f1.z,f1.w};
    #pragma unroll
    for (int j = 0; j < 8; j++) {
      u16 t0, t1;
      split2(qv[j], t0, t1);
      aq[0][hf][j] = (short)t0; aq[1][hf][j] = (short)t1;
    }
  }
  f32x4 Oacc[4];
  #pragma unroll
  for (int n = 0; n < 4; n++) Oacc[n] = {0.f,0.f,0.f,0.f};
  float mrow[4] = {-1e30f,-1e30f,-1e30f,-1e30f};
  float lrow[4] = {0.f,0.f,0.f,0.f};
  for (int kt = 0; kt <= qt; kt++) {
    __syncthreads();
    { // stage V transposed: lane owns kv-row `lane`, wave owns hd-range w*16
      int kvr = lane;
      const float* vs = v + (tokbase + kt*64 + kvr) * 256 + kvh * 64 + w*16;
      float4 f0 = *(const float4*)vs;
      float4 f1 = *(const float4*)(vs + 4);
      float4 f2 = *(const float4*)(vs + 8);
      float4 f3 = *(const float4*)(vs + 12);
      float vvv[16] = {f0.x,f0.y,f0.z,f0.w, f1.x,f1.y,f1.z,f1.w,
                       f2.x,f2.y,f2.z,f2.w, f3.x,f3.y,f3.z,f3.w};
      #pragma unroll
      for (int j = 0; j < 16; j++) {
        u16 t0, t1;
        split2(vvv[j], t0, t1);
        Vt[0][w*16 + j][kvr] = t0;
        Vt[1][w*16 + j][kvr] = t1;
      }
    }
    // S = (Q K^T)/8
    float sv[4][4];
    #pragma unroll
    for (int n = 0; n < 4; n++) {
      const float* krow = k + (tokbase + kt*64 + n*16 + lr) * 256 + kvh * 64;
      short8 bk_[2][2];
      #pragma unroll
      for (int hf = 0; hf < 2; hf++) {
        float4 f0 = *(const float4*)(krow + hf*32 + lg*8);
        float4 f1 = *(const float4*)(krow + hf*32 + lg*8 + 4);
        float kv_[8] = {f0.x,f0.y,f0.z,f0.w, f1.x,f1.y,f1.z,f1.w};
        #pragma unroll
        for (int j = 0; j < 8; j++) {
          u16 t0, t1;
          split2(kv_[j], t0, t1);
          bk_[0][hf][j] = (short)t0; bk_[1][hf][j] = (short)t1;
        }
      }
      f32x4 c = {0.f,0.f,0.f,0.f};
      #pragma unroll
      for (int hf = 0; hf < 2; hf++) {
        c = __builtin_amdgcn_mfma_f32_16x16x32_bf16(aq[0][hf], bk_[0][hf], c, 0, 0, 0);
        c = __builtin_amdgcn_mfma_f32_16x16x32_bf16(aq[0][hf], bk_[1][hf], c, 0, 0, 0);
        c = __builtin_amdgcn_mfma_f32_16x16x32_bf16(aq[1][hf], bk_[0][hf], c, 0, 0, 0);
      }
      #pragma unroll
      for (int r = 0; r < 4; r++) sv[n][r] = c[r] * 0.125f;
    }
    if (kt == qt) {
      #pragma unroll
      for (int n = 0; n < 4; n++)
        #pragma unroll
        for (int r = 0; r < 4; r++)
          if (n*16 + lr > w*16 + lg*4 + r) sv[n][r] = -1e30f;
    }
    float pvv[4][4];
    float alpha[4];
    #pragma unroll
    for (int r = 0; r < 4; r++) {
      float vm = fmaxf(fmaxf(sv[0][r], sv[1][r]), fmaxf(sv[2][r], sv[3][r]));
      #pragma unroll
      for (int msk = 1; msk < 16; msk <<= 1) vm = fmaxf(vm, __shfl_xor(vm, msk));
      float mnew = fmaxf(mrow[r], vm);
      alpha[r] = expf(mrow[r] - mnew);
      float psum = 0.f;
      #pragma unroll
      for (int n = 0; n < 4; n++) { pvv[n][r] = expf(sv[n][r] - mnew); psum += pvv[n][r]; }
      #pragma unroll
      for (int msk = 1; msk < 16; msk <<= 1) psum += __shfl_xor(psum, msk);
      lrow[r] = lrow[r] * alpha[r] + psum;
      mrow[r] = mnew;
    }
    #pragma unroll
    for (int n = 0; n < 4; n++)
      #pragma unroll
      for (int r = 0; r < 4; r++) {
        u16 t0, t1;
        split2(pvv[n][r], t0, t1);
        Ps[0][w][lg*4 + r][n*16 + lr] = t0;
        Ps[1][w][lg*4 + r][n*16 + lr] = t1;
      }
    #pragma unroll
    for (int n = 0; n < 4; n++)
      #pragma unroll
      for (int r = 0; r < 4; r++) Oacc[n][r] *= alpha[r];
    __syncthreads();
    // O += P V, 3 passes
    #pragma unroll
    for (int kk = 0; kk < 2; kk++) {
      short8 ap0 = *(const short8*)&Ps[0][w][lr][kk*32 + lg*8];
      short8 ap1 = *(const short8*)&Ps[1][w][lr][kk*32 + lg*8];
      #pragma unroll
      for (int n = 0; n < 4; n++) {
        short8 bv0 = *(const short8*)&Vt[0][n*16 + lr][kk*32 + lg*8];
        short8 bv1 = *(const short8*)&Vt[1][n*16 + lr][kk*32 + lg*8];
        f32x4 a = Oacc[n];
        a = __builtin_amdgcn_mfma_f32_16x16x32_bf16(ap0, bv0, a, 0, 0, 0);
        a = __builtin_amdgcn_mfma_f32_16x16x32_bf16(ap0, bv1, a, 0, 0, 0);
        a = __builtin_amdgcn_mfma_f32_16x16x32_bf16(ap1, bv0, a, 0, 0, 0);
        Oacc[n] = a;
      }
    }
  }
  float* orow = o + (tokbase + q0 + w*16) * 1024 + h * 64;
  #pragma unroll
  for (int n = 0; n < 4; n++)
    #pragma unroll
    for (int r = 0; r < 4; r++)
      orow[(lg*4 + r) * 1024 + n*16 + lr] = Oacc[n][r] / lrow[r];
}

// ---------------- router (pure fp32) ----------------
__global__ __launch_bounds__(64)
void router_kernel(const float* __restrict__ x, const float* __restrict__ w2,
                   const float* __restrict__ wr, int* __restrict__ tok_e,
                   float* __restrict__ tok_w, int* __restrict__ counts)
{
  int t = blockIdx.x, l = threadIdx.x;
  const float* xr = x + (long)t * HDIM;
  float xv[16];
  float ss = 0.f;
  #pragma unroll
  for (int j = 0; j < 16; j++) { xv[j] = xr[l + j*64]; ss += xv[j]*xv[j]; }
  #pragma unroll
  for (int m = 32; m; m >>= 1) ss += __shfl_xor(ss, m);
  float sc = 1.0f / sqrtf(ss * (1.f/HDIM) + RMS_EPS);
  float acc[8] = {0,0,0,0,0,0,0,0};
  #pragma unroll
  for (int j = 0; j < 16; j++) {
    int hh = l + j*64;
    float xnv = xv[j] * sc * w2[hh];
    const float* wrow = wr + hh * 8;
    #pragma unroll
    for (int e = 0; e < 8; e++) acc[e] += xnv * wrow[e];
  }
  #pragma unroll
  for (int e = 0; e < 8; e++)
    #pragma unroll
    for (int m = 32; m; m >>= 1) acc[e] += __shfl_xor(acc[e], m);
  if (l == 0) {
    float mx = acc[0];
    #pragma unroll
    for (int e = 1; e < 8; e++) mx = fmaxf(mx, acc[e]);
    float ex[8], s = 0.f;
    #pragma unroll
    for (int e = 0; e < 8; e++) { ex[e] = expf(acc[e] - mx); s += ex[e]; }
    int e0 = 0;
    #pragma unroll
    for (int e = 1; e < 8; e++) if (ex[e] > ex[e0]) e0 = e;
    int e1 = (e0 == 0) ? 1 : 0;
    for (int e = 0; e < 8; e++) if (e != e0 && ex[e] > ex[e1]) e1 = e;
    float v0 = ex[e0] / s, v1 = ex[e1] / s, wsum = v0 + v1;
    tok_e[2*t] = e0; tok_e[2*t+1] = e1;
    tok_w[2*t] = v0 / wsum; tok_w[2*t+1] = v1 / wsum;
    atomicAdd(&counts[e0], 1);
    atomicAdd(&counts[e1], 1);
  }
}

__global__ void scan_kernel(const int* __restrict__ counts, int* __restrict__ offs,
                            int* __restrict__ cursor) {
  if (threadIdx.x == 0 && blockIdx.x == 0) {
    int s = 0;
    for (int e = 0; e < NEXP; e++) { offs[e] = s; cursor[e] = s; s += counts[e]; }
    offs[NEXP] = s;
  }
}

__global__ __launch_bounds__(256)
void scatter_kernel(const int* __restrict__ tok_e, int* __restrict__ cursor,
                    int* __restrict__ tok_of_pair, int* __restrict__ tok_slot) {
  int t = blockIdx.x * 256 + threadIdx.x;
  if (t >= NTOK) return;
  #pragma unroll
  for (int s = 0; s < 2; s++) {
    int e = tok_e[2*t + s];
    int pos = atomicAdd(&cursor[e], 1);
    tok_of_pair[pos] = t;
    tok_slot[2*t + s] = pos;
  }
}

// x = clip(x + w0*po[s0] + w1*po[s1])
__global__ __launch_bounds__(256)
void combine_kernel(float* __restrict__ x, const float* __restrict__ po,
                    const int* __restrict__ tok_slot, const float* __restrict__ tok_w) {
  int t = blockIdx.x, tid = threadIdx.x;
  long s0 = tok_slot[2*t], s1 = tok_slot[2*t+1];
  float w0 = tok_w[2*t], w1 = tok_w[2*t+1];
  int c = tid * 4;
  float4 xv = *(float4*)(x + (long)t*HDIM + c);
  float4 a  = *(const float4*)(po + s0*HDIM + c);
  float4 bb = *(const float4*)(po + s1*HDIM + c);
  xv.x = clip100(xv.x + w0*a.x + w1*bb.x);
  xv.y = clip100(xv.y + w0*a.y + w1*bb.y);
  xv.z = clip100(xv.z + w0*a.z + w1*bb.z);
  xv.w = clip100(xv.w + w0*a.w + w1*bb.w);
  *(float4*)(x + (long)t*HDIM + c) = xv;
}

extern "C" void kernel_launch(void* const* d_in, const int* in_sizes, int n_in,
                              void* d_out, int out_size, void* d_ws, size_t ws_size,
                              hipStream_t stream)
{
  (void)in_sizes; (void)n_in; (void)out_size; (void)ws_size;
  const float* hs  = (const float*)d_in[0];
  const float* ln1 = (const float*)d_in[1];
  const float* ln2 = (const float*)d_in[2];
  const float* wq  = (const float*)d_in[3];
  const float* wk  = (const float*)d_in[4];
  const float* wvv = (const float*)d_in[5];
  const float* wo  = (const float*)d_in[6];
  const float* wr  = (const float*)d_in[7];
  const float* wg  = (const float*)d_in[8];
  const float* wu  = (const float*)d_in[9];
  const float* wd  = (const float*)d_in[10];
  float* x = (float*)d_out;

  char* p = (char*)d_ws;
  auto carve = [&](size_t bytes) {
    char* r = p; p += (bytes + 255) & ~(size_t)255; return r;
  };
  float* tab = (float*)carve((size_t)SEQ * 32 * 2 * 4);
  float* xn  = (float*)carve((size_t)NTOK * HDIM * 4);
  char*  big = carve((size_t)NPAIR * FFDIM * 4);
  float* qb  = (float*)big;
  float* kb  = (float*)(big + (size_t)NTOK * 1024 * 4);
  float* vb  = (float*)(big + (size_t)NTOK * 1024 * 4 + (size_t)NTOK * 256 * 4);
  float* ao  = (float*)(big + (size_t)NTOK * 1024 * 4 + (size_t)NTOK * 512 * 4);
  float* g   = (float*)big;
  float* po  = (float*)carve((size_t)NPAIR * HDIM * 4);
  int*   tok_e       = (int*)carve(NTOK * 2 * 4);
  float* tok_w       = (float*)carve(NTOK * 2 * 4);
  int*   tok_slot    = (int*)carve(NTOK * 2 * 4);
  int*   tok_of_pair = (int*)carve(NPAIR * 4);
  int*   counts      = (int*)carve(8 * 4);
  int*   offs        = (int*)carve(9 * 4);
  int*   cursor      = (int*)carve(8 * 4);

  hipMemcpyAsync(x, hs, (size_t)NTOK * HDIM * 4, hipMemcpyDeviceToDevice, stream);
  rope_table_kernel<<<SEQ*32/256, 256, 0, stream>>>(tab);

  for (int l = 0; l < NLAYER; l++) {
    rmsnorm_kernel<<<NTOK, 256, 0, stream>>>(x, ln1 + (long)l*HDIM, xn);
    gemm_kernel<0><<<dim3(8, 32, 1), 256, 0, stream>>>(
        xn, wq + (long)l*HDIM*1024, qb, nullptr, nullptr, NTOK, 1024, HDIM, 0);
    gemm_kernel<0><<<dim3(2, 32, 1), 256, 0, stream>>>(
        xn, wk + (long)l*HDIM*256, kb, nullptr, nullptr, NTOK, 256, HDIM, 0);
    gemm_kernel<0><<<dim3(2, 32, 1), 256, 0, stream>>>(
        xn, wvv + (long)l*HDIM*256, vb, nullptr, nullptr, NTOK, 256, HDIM, 0);
    rope_kernel<<<(NTOK*20*32)/256, 256, 0, stream>>>(qb, kb, tab);
    attn_kernel<<<dim3(SEQ/64, NHEAD, NBATCH), 256, 0, stream>>>(qb, kb, vb, ao);
    gemm_kernel<2><<<dim3(8, 32, 1), 256, 0, stream>>>(
        ao, wo + (long)l*1024*HDIM, x, nullptr, nullptr, NTOK, HDIM, 1024, 0);

    rmsnorm_kernel<<<NTOK, 256, 0, stream>>>(x, ln2 + (long)l*HDIM, xn);
    hipMemsetAsync(counts, 0, 8 * 4, stream);
    router_kernel<<<NTOK, 64, 0, stream>>>(
        x, ln2 + (long)l*HDIM, wr + (long)l*HDIM*NEXP, tok_e, tok_w, counts);
    scan_kernel<<<1, 64, 0, stream>>>(counts, offs, cursor);
    scatter_kernel<<<NTOK/256, 256, 0, stream>>>(tok_e, cursor, tok_of_pair, tok_slot);
    gemm_kernel<0><<<dim3(16, 32, 8), 256, 0, stream>>>(
        xn, wg + (long)l*NEXP*HDIM*FFDIM, g, tok_of_pair, offs,
        0, FFDIM, HDIM, (long)HDIM*FFDIM);
    gemm_kernel<3><<<dim3(16, 32, 8), 256, 0, stream>>>(
        xn, wu + (long)l*NEXP*HDIM*FFDIM, g, tok_of_pair, offs,
        0, FFDIM, HDIM, (long)HDIM*FFDIM);
    gemm_kernel<0><<<dim3(8, 32, 8), 256, 0, stream>>>(
        g, wd + (long)l*NEXP*FFDIM*HDIM, po, nullptr, offs,
        0, HDIM, FFDIM, (long)FFDIM*HDIM);
    combine_kernel<<<NTOK, 256, 0, stream>>>(x, po, tok_slot, tok_w);
  }
}

// Round 4
// 5726.068 us; speedup vs baseline: 1.7453x; 1.0906x over previous
//
#include <hip/hip_runtime.h>
#include <math.h>

typedef unsigned short u16;
typedef short short8 __attribute__((ext_vector_type(8)));
typedef short short4v __attribute__((ext_vector_type(4)));
typedef float f32x4 __attribute__((ext_vector_type(4)));

#define NLAYER 4
#define HDIM 1024
#define NHEAD 16
#define NKVH 4
#define FFDIM 2048
#define NEXP 8
#define SEQ 2048
#define NBATCH 2
#define NTOK (NBATCH*SEQ)
#define NPAIR (NTOK*2)
#define RMS_EPS 1e-5f

// ---- 2-term bf16 split: x = b2f(o0)+b2f(o1) + O(x*2^-18) ----
__device__ __forceinline__ u16 b16(float x) {
  unsigned u = __builtin_bit_cast(unsigned, x);
  unsigned r = (u + 0x7FFFu + ((u >> 16) & 1u)) >> 16;
  return (u16)r;
}
__device__ __forceinline__ float b2f(u16 b) {
  return __builtin_bit_cast(float, ((unsigned)b) << 16);
}
__device__ __forceinline__ void split2(float x, u16& o0, u16& o1) {
  o0 = b16(x); o1 = b16(x - b2f(o0));
}
__device__ __forceinline__ float clip100(float v) {
  return fminf(fmaxf(v, -100.f), 100.f);
}

// ---------------- RMSNorm: fp32 -> pre-split bf16 hi/lo ----------------
__global__ __launch_bounds__(256)
void rmsnorm_kernel(const float* __restrict__ x, const float* __restrict__ w,
                    u16* __restrict__ oh, u16* __restrict__ ol) {
  int t = blockIdx.x, tid = threadIdx.x;
  const float* xr = x + (long)t * HDIM;
  float4 v = *(const float4*)(xr + tid * 4);
  float ss = v.x*v.x + v.y*v.y + v.z*v.z + v.w*v.w;
  #pragma unroll
  for (int m = 32; m; m >>= 1) ss += __shfl_xor(ss, m);
  __shared__ float sb[4];
  if ((tid & 63) == 0) sb[tid >> 6] = ss;
  __syncthreads();
  ss = sb[0] + sb[1] + sb[2] + sb[3];
  float sc = 1.0f / sqrtf(ss * (1.f/HDIM) + RMS_EPS);
  float4 wv = *(const float4*)(w + tid * 4);
  float ov[4] = {v.x*sc*wv.x, v.y*sc*wv.y, v.z*sc*wv.z, v.w*sc*wv.w};
  short4v hv, lv;
  #pragma unroll
  for (int j = 0; j < 4; j++) { u16 h, l; split2(ov[j], h, l); hv[j]=(short)h; lv[j]=(short)l; }
  *(short4v*)&oh[(long)t*HDIM + tid*4] = hv;
  *(short4v*)&ol[(long)t*HDIM + tid*4] = lv;
}

// ---------------- RoPE cos/sin table (matches np f32 semantics) ----------------
__global__ __launch_bounds__(256)
void rope_table_kernel(float* __restrict__ tab) {
  int idx = blockIdx.x * 256 + threadIdx.x;   // SEQ*32
  int i = idx & 31, pos = idx >> 5;
  double e = -(double)i * 0.28782313662425575;   // ln(10000)/32
  float inv = (float)exp(e);
  float f = (float)pos * inv;
  tab[idx] = cosf(f);
  tab[SEQ*32 + idx] = sinf(f);
}

// =========== shared GEMM core: BM=256, BN=64, BK=32, 256 thr, 4 waves ==========
// A pre-split bf16 hi/lo [rows][K]; B fp32 [K][N] split in-kernel (3-pass).
#define GPAD 40

#define GEMM_CORE(A_ROW_VALID)                                                 \
  f32x4 acc[4][4];                                                             \
  _Pragma("unroll") for (int m = 0; m < 4; m++)                                \
    _Pragma("unroll") for (int n = 0; n < 4; n++) acc[m][n] = {0.f,0.f,0.f,0.f};\
  int b_col = tid & 63;                                                        \
  int b_kh = (tid >> 6) * 8;                                                   \
  for (int k0 = 0; k0 < K; k0 += 32) {                                         \
    if (A_ROW_VALID) {                                                         \
      const u16* ah = Ah + arow * (long)K + k0;                                \
      const u16* al = Al + arow * (long)K + k0;                                \
      _Pragma("unroll") for (int q = 0; q < 4; q++) {                          \
        *(short8*)&As[0][tid][q*8] = *(const short8*)(ah + q*8);               \
        *(short8*)&As[1][tid][q*8] = *(const short8*)(al + q*8);               \
      }                                                                        \
    } else {                                                                   \
      short8 z = {0,0,0,0,0,0,0,0};                                            \
      _Pragma("unroll") for (int q = 0; q < 4; q++) {                          \
        *(short8*)&As[0][tid][q*8] = z; *(short8*)&As[1][tid][q*8] = z;        \
      }                                                                        \
    }                                                                          \
    {                                                                          \
      const float* bp = Bp + (long)(k0 + b_kh) * Nb + bcol0 + b_col;           \
      short8 hv, lv;                                                           \
      _Pragma("unroll") for (int j = 0; j < 8; j++) {                          \
        u16 h, l; split2(bp[(long)j * Nb], h, l);                              \
        hv[j] = (short)h; lv[j] = (short)l;                                    \
      }                                                                        \
      *(short8*)&Bs[0][b_col][b_kh] = hv;                                      \
      *(short8*)&Bs[1][b_col][b_kh] = lv;                                      \
    }                                                                          \
    __syncthreads();                                                           \
    short8 bf[2][4];                                                           \
    _Pragma("unroll") for (int t = 0; t < 2; t++)                              \
      _Pragma("unroll") for (int n = 0; n < 4; n++)                            \
        bf[t][n] = *(const short8*)&Bs[t][n*16 + lr][lg*8];                    \
    _Pragma("unroll") for (int m = 0; m < 4; m++) {                            \
      short8 afh = *(const short8*)&As[0][wr + m*16 + lr][lg*8];               \
      short8 afl = *(const short8*)&As[1][wr + m*16 + lr][lg*8];               \
      _Pragma("unroll") for (int n = 0; n < 4; n++) {                          \
        f32x4 a = acc[m][n];                                                   \
        a = __builtin_amdgcn_mfma_f32_16x16x32_bf16(afh, bf[0][n], a, 0, 0, 0);\
        a = __builtin_amdgcn_mfma_f32_16x16x32_bf16(afh, bf[1][n], a, 0, 0, 0);\
        a = __builtin_amdgcn_mfma_f32_16x16x32_bf16(afl, bf[0][n], a, 0, 0, 0);\
        acc[m][n] = a;                                                         \
      }                                                                        \
    }                                                                          \
    __syncthreads();                                                           \
  }

// MODE 0: Cf = acc ; MODE 2: Cf = clip(Cf+acc) ; MODE 3: h=silu(Cf)*acc -> Ch/Cl
template<int MODE>
__global__ __launch_bounds__(256, 3)
void gemm_moe(const u16* __restrict__ Ah, const u16* __restrict__ Al,
              const float* __restrict__ B, float* __restrict__ Cf,
              u16* __restrict__ Ch, u16* __restrict__ Cl,
              const int* __restrict__ gather, const int* __restrict__ offs,
              int M, int N, int K, long bstride)
{
  __shared__ u16 As[2][256][GPAD];
  __shared__ u16 Bs[2][64][GPAD];
  int rs, re;
  if (offs) { rs = offs[blockIdx.z]; re = offs[blockIdx.z + 1]; }
  else      { rs = 0;               re = M; }
  int p0 = rs + blockIdx.y * 256;
  if (p0 >= re) return;
  int bcol0 = blockIdx.x * 64;
  const float* Bp = B + (long)blockIdx.z * bstride;
  int Nb = N;
  int tid = threadIdx.x, wv = tid >> 6, lane = tid & 63;
  int lr = lane & 15, lg = lane >> 4;
  int wr = wv * 64;
  long arow = -1;
  { int rr = p0 + tid; if (rr < re) arow = gather ? gather[rr] : rr; }
  GEMM_CORE(arow >= 0)
  #pragma unroll
  for (int m = 0; m < 4; m++) {
    int row0 = p0 + wr + m*16 + lg*4;
    #pragma unroll
    for (int n = 0; n < 4; n++) {
      int col = bcol0 + n*16 + lr;
      #pragma unroll
      for (int r = 0; r < 4; r++) {
        int row = row0 + r;
        if (row < re) {
          float vvv = acc[m][n][r];
          long idx = (long)row * N + col;
          if constexpr (MODE == 0) Cf[idx] = vvv;
          else if constexpr (MODE == 2) Cf[idx] = clip100(Cf[idx] + vvv);
          else {
            float gv = Cf[idx];
            float hh = gv / (1.f + __expf(-gv)) * vvv;
            u16 h, l; split2(hh, h, l);
            Ch[idx] = h; Cl[idx] = l;
          }
        }
      }
    }
  }
}

// fused QKV GEMM: x-blocks 0..15 -> q (rope+split), 16..19 -> k (rope+split),
// 20..23 -> v (split + transpose to [b][kvh][hd][seq])
__global__ __launch_bounds__(256, 3)
void gemm_qkv(const u16* __restrict__ Ah, const u16* __restrict__ Al,
              const float* __restrict__ wq, const float* __restrict__ wk,
              const float* __restrict__ wv_, const float* __restrict__ tab,
              u16* __restrict__ qh, u16* __restrict__ ql,
              u16* __restrict__ kh_, u16* __restrict__ kl_,
              u16* __restrict__ vth, u16* __restrict__ vtl)
{
  __shared__ u16 As[2][256][GPAD];
  __shared__ u16 Bs[2][64][GPAD];
  int bx = blockIdx.x;
  int p0 = blockIdx.y * 256;
  const float* Bp; int Nb, bcol0;
  if (bx < 16)      { Bp = wq;  Nb = 1024; bcol0 = bx * 64; }
  else if (bx < 20) { Bp = wk;  Nb = 256;  bcol0 = (bx - 16) * 64; }
  else              { Bp = wv_; Nb = 256;  bcol0 = (bx - 20) * 64; }
  int K = HDIM;
  int tid = threadIdx.x, wv = tid >> 6, lane = tid & 63;
  int lr = lane & 15, lg = lane >> 4;
  int wr = wv * 64;
  long arow = p0 + tid;
  GEMM_CORE(true)
  if (bx < 16) {          // ---- q: rope + split ----
    int h = bx;
    #pragma unroll
    for (int m = 0; m < 4; m++) {
      #pragma unroll
      for (int r = 0; r < 4; r++) {
        int tok = p0 + wr + m*16 + lg*4 + r;
        int pos = tok & (SEQ - 1);
        #pragma unroll
        for (int n = 0; n < 2; n++) {
          int i = n*16 + lr;
          float c = tab[pos*32 + i], s = tab[SEQ*32 + pos*32 + i];
          float x0 = acc[m][n][r], x1 = acc[m][n+2][r];
          float y0 = x0*c - x1*s, y1 = x1*c + x0*s;
          long base = (long)tok*1024 + h*64 + i;
          u16 h0, l0; split2(y0, h0, l0); qh[base] = h0; ql[base] = l0;
          u16 h1, l1; split2(y1, h1, l1); qh[base+32] = h1; ql[base+32] = l1;
        }
      }
    }
  } else if (bx < 20) {   // ---- k: rope + split ----
    int kvh = bx - 16;
    #pragma unroll
    for (int m = 0; m < 4; m++) {
      #pragma unroll
      for (int r = 0; r < 4; r++) {
        int tok = p0 + wr + m*16 + lg*4 + r;
        int pos = tok & (SEQ - 1);
        #pragma unroll
        for (int n = 0; n < 2; n++) {
          int i = n*16 + lr;
          float c = tab[pos*32 + i], s = tab[SEQ*32 + pos*32 + i];
          float x0 = acc[m][n][r], x1 = acc[m][n+2][r];
          float y0 = x0*c - x1*s, y1 = x1*c + x0*s;
          long base = (long)tok*256 + kvh*64 + i;
          u16 h0, l0; split2(y0, h0, l0); kh_[base] = h0; kl_[base] = l0;
          u16 h1, l1; split2(y1, h1, l1); kh_[base+32] = h1; kl_[base+32] = l1;
        }
      }
    }
  } else {                // ---- v: split + transpose ----
    int kvh = bx - 20;
    #pragma unroll
    for (int m = 0; m < 4; m++) {
      #pragma unroll
      for (int r = 0; r < 4; r++) {
        int tok = p0 + wr + m*16 + lg*4 + r;
        int bb = tok >> 11, tl = tok & (SEQ - 1);
        #pragma unroll
        for (int n = 0; n < 4; n++) {
          int hd = n*16 + lr;
          u16 h0, l0; split2(acc[m][n][r], h0, l0);
          long vidx = ((long)(bb*NKVH + kvh)*64 + hd)*SEQ + tl;
          vth[vidx] = h0; vtl[vidx] = l0;
        }
      }
    }
  }
}

// ---------------- causal flash attention, pre-split inputs ----------------
#define ATP 72
__global__ __launch_bounds__(256)
void attn_kernel(const u16* __restrict__ qhi, const u16* __restrict__ qlo,
                 const u16* __restrict__ khi, const u16* __restrict__ klo,
                 const u16* __restrict__ vthi, const u16* __restrict__ vtlo,
                 u16* __restrict__ ohi, u16* __restrict__ olo)
{
  int qp = blockIdx.x, h = blockIdx.y, b = blockIdx.z;
  int kvh = h >> 2;
  int tid = threadIdx.x, w = tid >> 6, lane = tid & 63;
  int lr = lane & 15, lg = lane >> 4;
  __shared__ u16 KhS[64][ATP], KlS[64][ATP], VhS[64][ATP], VlS[64][ATP];
  __shared__ u16 Ps[2][4][16][ATP];
  long tokbase = (long)b * SEQ;
  int sr = tid >> 2, scg = (tid & 3) * 16;          // staging: row, col-chunk
  const u16* vrow_h = vthi + ((long)(b*NKVH + kvh)*64 + sr)*SEQ;
  const u16* vrow_l = vtlo + ((long)(b*NKVH + kvh)*64 + sr)*SEQ;

  for (int ph = 0; ph < 2; ph++) {
    int qt = ph ? (31 - qp) : qp;
    long q0 = (long)qt * 64;
    const u16* qh_row = qhi + (tokbase + q0 + w*16 + lr)*1024 + h*64;
    const u16* ql_row = qlo + (tokbase + q0 + w*16 + lr)*1024 + h*64;
    short8 aqh[2], aql[2];
    #pragma unroll
    for (int hf = 0; hf < 2; hf++) {
      aqh[hf] = *(const short8*)(qh_row + hf*32 + lg*8);
      aql[hf] = *(const short8*)(ql_row + hf*32 + lg*8);
    }
    f32x4 Oacc[4];
    #pragma unroll
    for (int n = 0; n < 4; n++) Oacc[n] = {0.f,0.f,0.f,0.f};
    float mrow[4] = {-1e30f,-1e30f,-1e30f,-1e30f};
    float lrow[4] = {0.f,0.f,0.f,0.f};
    for (int kt = 0; kt <= qt; kt++) {
      if (ph | kt) __syncthreads();   // protect LDS from previous tile's readers
      { // stage K and V (hi/lo) cooperatively
        long kg = (tokbase + kt*64 + sr)*256 + kvh*64 + scg;
        *(short8*)&KhS[sr][scg]   = *(const short8*)(khi + kg);
        *(short8*)&KhS[sr][scg+8] = *(const short8*)(khi + kg + 8);
        *(short8*)&KlS[sr][scg]   = *(const short8*)(klo + kg);
        *(short8*)&KlS[sr][scg+8] = *(const short8*)(klo + kg + 8);
        long vg = kt*64 + scg;
        *(short8*)&VhS[sr][scg]   = *(const short8*)(vrow_h + vg);
        *(short8*)&VhS[sr][scg+8] = *(const short8*)(vrow_h + vg + 8);
        *(short8*)&VlS[sr][scg]   = *(const short8*)(vrow_l + vg);
        *(short8*)&VlS[sr][scg+8] = *(const short8*)(vrow_l + vg + 8);
      }
      __syncthreads();
      // S = (Q K^T)/8, 3-pass
      float sv[4][4];
      #pragma unroll
      for (int n = 0; n < 4; n++) {
        short8 bh0 = *(const short8*)&KhS[n*16 + lr][lg*8];
        short8 bh1 = *(const short8*)&KhS[n*16 + lr][32 + lg*8];
        short8 bl0 = *(const short8*)&KlS[n*16 + lr][lg*8];
        short8 bl1 = *(const short8*)&KlS[n*16 + lr][32 + lg*8];
        f32x4 c = {0.f,0.f,0.f,0.f};
        c = __builtin_amdgcn_mfma_f32_16x16x32_bf16(aqh[0], bh0, c, 0, 0, 0);
        c = __builtin_amdgcn_mfma_f32_16x16x32_bf16(aqh[1], bh1, c, 0, 0, 0);
        c = __builtin_amdgcn_mfma_f32_16x16x32_bf16(aqh[0], bl0, c, 0, 0, 0);
        c = __builtin_amdgcn_mfma_f32_16x16x32_bf16(aqh[1], bl1, c, 0, 0, 0);
        c = __builtin_amdgcn_mfma_f32_16x16x32_bf16(aql[0], bh0, c, 0, 0, 0);
        c = __builtin_amdgcn_mfma_f32_16x16x32_bf16(aql[1], bh1, c, 0, 0, 0);
        #pragma unroll
        for (int r = 0; r < 4; r++) sv[n][r] = c[r] * 0.125f;
      }
      if (kt == qt) {
        #pragma unroll
        for (int n = 0; n < 4; n++)
          #pragma unroll
          for (int r = 0; r < 4; r++)
            if (n*16 + lr > w*16 + lg*4 + r) sv[n][r] = -1e30f;
      }
      float pvv[4][4], alpha[4];
      #pragma unroll
      for (int r = 0; r < 4; r++) {
        float vm = fmaxf(fmaxf(sv[0][r], sv[1][r]), fmaxf(sv[2][r], sv[3][r]));
        #pragma unroll
        for (int msk = 1; msk < 16; msk <<= 1) vm = fmaxf(vm, __shfl_xor(vm, msk));
        float mnew = fmaxf(mrow[r], vm);
        alpha[r] = __expf(mrow[r] - mnew);
        float psum = 0.f;
        #pragma unroll
        for (int n = 0; n < 4; n++) { pvv[n][r] = __expf(sv[n][r] - mnew); psum += pvv[n][r]; }
        #pragma unroll
        for (int msk = 1; msk < 16; msk <<= 1) psum += __shfl_xor(psum, msk);
        lrow[r] = lrow[r] * alpha[r] + psum;
        mrow[r] = mnew;
      }
      #pragma unroll
      for (int n = 0; n < 4; n++)
        #pragma unroll
        for (int r = 0; r < 4; r++) {
          u16 t0, t1;
          split2(pvv[n][r], t0, t1);
          Ps[0][w][lg*4 + r][n*16 + lr] = t0;
          Ps[1][w][lg*4 + r][n*16 + lr] = t1;
        }
      #pragma unroll
      for (int n = 0; n < 4; n++)
        #pragma unroll
        for (int r = 0; r < 4; r++) Oacc[n][r] *= alpha[r];
      // PV (Ps is per-wave; V protected by loop-top barrier)
      #pragma unroll
      for (int kk = 0; kk < 2; kk++) {
        short8 aph = *(const short8*)&Ps[0][w][lr][kk*32 + lg*8];
        short8 apl = *(const short8*)&Ps[1][w][lr][kk*32 + lg*8];
        #pragma unroll
        for (int n = 0; n < 4; n++) {
          short8 bvh = *(const short8*)&VhS[n*16 + lr][kk*32 + lg*8];
          short8 bvl = *(const short8*)&VlS[n*16 + lr][kk*32 + lg*8];
          f32x4 a = Oacc[n];
          a = __builtin_amdgcn_mfma_f32_16x16x32_bf16(aph, bvh, a, 0, 0, 0);
          a = __builtin_amdgcn_mfma_f32_16x16x32_bf16(aph, bvl, a, 0, 0, 0);
          a = __builtin_amdgcn_mfma_f32_16x16x32_bf16(apl, bvh, a, 0, 0, 0);
          Oacc[n] = a;
        }
      }
    }
    u16* oh_row = ohi + (tokbase + q0 + w*16)*1024 + h*64;
    u16* ol_row = olo + (tokbase + q0 + w*16)*1024 + h*64;
    #pragma unroll
    for (int n = 0; n < 4; n++)
      #pragma unroll
      for (int r = 0; r < 4; r++) {
        float v = Oacc[n][r] / lrow[r];
        u16 h0, l0; split2(v, h0, l0);
        oh_row[(lg*4 + r)*1024 + n*16 + lr] = h0;
        ol_row[(lg*4 + r)*1024 + n*16 + lr] = l0;
      }
  }
}

// ---------------- router (pure fp32) ----------------
__global__ __launch_bounds__(64)
void router_kernel(const float* __restrict__ x, const float* __restrict__ w2,
                   const float* __restrict__ wr, int* __restrict__ tok_e,
                   float* __restrict__ tok_w, int* __restrict__ counts)
{
  int t = blockIdx.x, l = threadIdx.x;
  const float* xr = x + (long)t * HDIM;
  float xv[16];
  float ss = 0.f;
  #pragma unroll
  for (int j = 0; j < 16; j++) { xv[j] = xr[l + j*64]; ss += xv[j]*xv[j]; }
  #pragma unroll
  for (int m = 32; m; m >>= 1) ss += __shfl_xor(ss, m);
  float sc = 1.0f / sqrtf(ss * (1.f/HDIM) + RMS_EPS);
  float acc[8] = {0,0,0,0,0,0,0,0};
  #pragma unroll
  for (int j = 0; j < 16; j++) {
    int hh = l + j*64;
    float xnv = xv[j] * sc * w2[hh];
    const float* wrow = wr + hh * 8;
    #pragma unroll
    for (int e = 0; e < 8; e++) acc[e] += xnv * wrow[e];
  }
  #pragma unroll
  for (int e = 0; e < 8; e++)
    #pragma unroll
    for (int m = 32; m; m >>= 1) acc[e] += __shfl_xor(acc[e], m);
  if (l == 0) {
    float mx = acc[0];
    #pragma unroll
    for (int e = 1; e < 8; e++) mx = fmaxf(mx, acc[e]);
    float ex[8], s = 0.f;
    #pragma unroll
    for (int e = 0; e < 8; e++) { ex[e] = expf(acc[e] - mx); s += ex[e]; }
    int e0 = 0;
    #pragma unroll
    for (int e = 1; e < 8; e++) if (ex[e] > ex[e0]) e0 = e;
    int e1 = (e0 == 0) ? 1 : 0;
    for (int e = 0; e < 8; e++) if (e != e0 && ex[e] > ex[e1]) e1 = e;
    float v0 = ex[e0] / s, v1 = ex[e1] / s, wsum = v0 + v1;
    tok_e[2*t] = e0; tok_e[2*t+1] = e1;
    tok_w[2*t] = v0 / wsum; tok_w[2*t+1] = v1 / wsum;
    atomicAdd(&counts[e0], 1);
    atomicAdd(&counts[e1], 1);
  }
}

__global__ void scan_kernel(const int* __restrict__ counts, int* __restrict__ offs,
                            int* __restrict__ cursor) {
  if (threadIdx.x == 0 && blockIdx.x == 0) {
    int s = 0;
    for (int e = 0; e < NEXP; e++) { offs[e] = s; cursor[e] = s; s += counts[e]; }
    offs[NEXP] = s;
  }
}

__global__ __launch_bounds__(256)
void scatter_kernel(const int* __restrict__ tok_e, int* __restrict__ cursor,
                    int* __restrict__ tok_of_pair, int* __restrict__ tok_slot) {
  int t = blockIdx.x * 256 + threadIdx.x;
  if (t >= NTOK) return;
  #pragma unroll
  for (int s = 0; s < 2; s++) {
    int e = tok_e[2*t + s];
    int pos = atomicAdd(&cursor[e], 1);
    tok_of_pair[pos] = t;
    tok_slot[2*t + s] = pos;
  }
}

// x = clip(x + w0*po[s0] + w1*po[s1])
__global__ __launch_bounds__(256)
void combine_kernel(float* __restrict__ x, const float* __restrict__ po,
                    const int* __restrict__ tok_slot, const float* __restrict__ tok_w) {
  int t = blockIdx.x, tid = threadIdx.x;
  long s0 = tok_slot[2*t], s1 = tok_slot[2*t+1];
  float w0 = tok_w[2*t], w1 = tok_w[2*t+1];
  int c = tid * 4;
  float4 xv = *(float4*)(x + (long)t*HDIM + c);
  float4 a  = *(const float4*)(po + s0*HDIM + c);
  float4 bb = *(const float4*)(po + s1*HDIM + c);
  xv.x = clip100(xv.x + w0*a.x + w1*bb.x);
  xv.y = clip100(xv.y + w0*a.y + w1*bb.y);
  xv.z = clip100(xv.z + w0*a.z + w1*bb.z);
  xv.w = clip100(xv.w + w0*a.w + w1*bb.w);
  *(float4*)(x + (long)t*HDIM + c) = xv;
}

extern "C" void kernel_launch(void* const* d_in, const int* in_sizes, int n_in,
                              void* d_out, int out_size, void* d_ws, size_t ws_size,
                              hipStream_t stream)
{
  (void)in_sizes; (void)n_in; (void)out_size; (void)ws_size;
  const float* hs  = (const float*)d_in[0];
  const float* ln1 = (const float*)d_in[1];
  const float* ln2 = (const float*)d_in[2];
  const float* wq  = (const float*)d_in[3];
  const float* wk  = (const float*)d_in[4];
  const float* wvv = (const float*)d_in[5];
  const float* wo  = (const float*)d_in[6];
  const float* wr  = (const float*)d_in[7];
  const float* wg  = (const float*)d_in[8];
  const float* wu  = (const float*)d_in[9];
  const float* wd  = (const float*)d_in[10];
  float* x = (float*)d_out;

  char* p = (char*)d_ws;
  auto carve = [&](size_t bytes) {
    char* r = p; p += (bytes + 255) & ~(size_t)255; return r;
  };
  float* tab = (float*)carve((size_t)SEQ * 32 * 2 * 4);
  u16* xnh = (u16*)carve((size_t)NTOK * HDIM * 2);
  u16* xnl = (u16*)carve((size_t)NTOK * HDIM * 2);
  char* R  = carve((size_t)128 * 1024 * 1024);   // shared attn / MoE region
  // attn phase layout
  u16* qhi = (u16*)R;                              // 8MB
  u16* qlo = (u16*)(R + 8u*1024*1024);             // 8MB
  u16* khi = (u16*)(R + 16u*1024*1024);            // 2MB
  u16* klo = (u16*)(R + 18u*1024*1024);            // 2MB
  u16* vthi= (u16*)(R + 20u*1024*1024);            // 2MB
  u16* vtlo= (u16*)(R + 22u*1024*1024);            // 2MB
  u16* ohi = (u16*)(R + 24u*1024*1024);            // 8MB
  u16* olo = (u16*)(R + 32u*1024*1024);            // 8MB
  // MoE phase layout (aliases attn)
  float* g   = (float*)R;                          // 64MB
  u16*   ghi = (u16*)(R + 64u*1024*1024);          // 32MB
  u16*   glo = (u16*)(R + 96u*1024*1024);          // 32MB
  float* po  = (float*)R;                          // 32MB (g dead after up-proj)
  int*   tok_e       = (int*)carve(NTOK * 2 * 4);
  float* tok_w       = (float*)carve(NTOK * 2 * 4);
  int*   tok_slot    = (int*)carve(NTOK * 2 * 4);
  int*   tok_of_pair = (int*)carve(NPAIR * 4);
  int*   counts      = (int*)carve(8 * 4);
  int*   offs        = (int*)carve(9 * 4);
  int*   cursor      = (int*)carve(8 * 4);

  hipMemcpyAsync(x, hs, (size_t)NTOK * HDIM * 4, hipMemcpyDeviceToDevice, stream);
  rope_table_kernel<<<SEQ*32/256, 256, 0, stream>>>(tab);

  for (int l = 0; l < NLAYER; l++) {
    rmsnorm_kernel<<<NTOK, 256, 0, stream>>>(x, ln1 + (long)l*HDIM, xnh, xnl);
    gemm_qkv<<<dim3(24, NTOK/256, 1), 256, 0, stream>>>(
        xnh, xnl, wq + (long)l*HDIM*1024, wk + (long)l*HDIM*256,
        wvv + (long)l*HDIM*256, tab, qhi, qlo, khi, klo, vthi, vtlo);
    attn_kernel<<<dim3(16, NHEAD, NBATCH), 256, 0, stream>>>(
        qhi, qlo, khi, klo, vthi, vtlo, ohi, olo);
    gemm_moe<2><<<dim3(16, NTOK/256, 1), 256, 0, stream>>>(
        ohi, olo, wo + (long)l*1024*HDIM, x, nullptr, nullptr,
        nullptr, nullptr, NTOK, HDIM, 1024, 0);

    rmsnorm_kernel<<<NTOK, 256, 0, stream>>>(x, ln2 + (long)l*HDIM, xnh, xnl);
    hipMemsetAsync(counts, 0, 8 * 4, stream);
    router_kernel<<<NTOK, 64, 0, stream>>>(
        x, ln2 + (long)l*HDIM, wr + (long)l*HDIM*NEXP, tok_e, tok_w, counts);
    scan_kernel<<<1, 64, 0, stream>>>(counts, offs, cursor);
    scatter_kernel<<<NTOK/256, 256, 0, stream>>>(tok_e, cursor, tok_of_pair, tok_slot);
    gemm_moe<0><<<dim3(32, 32, 8), 256, 0, stream>>>(
        xnh, xnl, wg + (long)l*NEXP*HDIM*FFDIM, g, nullptr, nullptr,
        tok_of_pair, offs, 0, FFDIM, HDIM, (long)HDIM*FFDIM);
    gemm_moe<3><<<dim3(32, 32, 8), 256, 0, stream>>>(
        xnh, xnl, wu + (long)l*NEXP*HDIM*FFDIM, g, ghi, glo,
        tok_of_pair, offs, 0, FFDIM, HDIM, (long)HDIM*FFDIM);
    gemm_moe<0><<<dim3(16, 32, 8), 256, 0, stream>>>(
        ghi, glo, wd + (long)l*NEXP*FFDIM*HDIM, po, nullptr, nullptr,
        nullptr, offs, 0, HDIM, FFDIM, (long)FFDIM*HDIM);
    combine_kernel<<<NTOK, 256, 0, stream>>>(x, po, tok_slot, tok_w);
  }
}

// Round 5
// 4385.056 us; speedup vs baseline: 2.2791x; 1.3058x over previous
//
#include <hip/hip_runtime.h>
#include <math.h>

typedef unsigned short u16;
typedef short short8 __attribute__((ext_vector_type(8)));
typedef short short4v __attribute__((ext_vector_type(4)));
typedef float f32x4 __attribute__((ext_vector_type(4)));

#define NLAYER 4
#define HDIM 1024
#define NHEAD 16
#define NKVH 4
#define FFDIM 2048
#define NEXP 8
#define SEQ 2048
#define NBATCH 2
#define NTOK (NBATCH*SEQ)
#define NPAIR (NTOK*2)
#define RMS_EPS 1e-5f

// ---- 2-term bf16 split: x = b2f(o0)+b2f(o1) + O(x*2^-18) ----
__device__ __forceinline__ u16 b16(float x) {
  unsigned u = __builtin_bit_cast(unsigned, x);
  unsigned r = (u + 0x7FFFu + ((u >> 16) & 1u)) >> 16;
  return (u16)r;
}
__device__ __forceinline__ float b2f(u16 b) {
  return __builtin_bit_cast(float, ((unsigned)b) << 16);
}
__device__ __forceinline__ void split2(float x, u16& o0, u16& o1) {
  o0 = b16(x); o1 = b16(x - b2f(o0));
}
__device__ __forceinline__ float clip100(float v) {
  return fminf(fmaxf(v, -100.f), 100.f);
}
// chunked XCD swizzle (nwg % 8 == 0): XCD x gets contiguous work chunk
__device__ __forceinline__ int swz8(int bid, int nwg) {
  return (bid & 7) * (nwg >> 3) + (bid >> 3);
}

// ---------------- RMSNorm: fp32 -> pre-split bf16 hi/lo ----------------
__global__ __launch_bounds__(256)
void rmsnorm_kernel(const float* __restrict__ x, const float* __restrict__ w,
                    u16* __restrict__ oh, u16* __restrict__ ol) {
  int t = blockIdx.x, tid = threadIdx.x;
  const float* xr = x + (long)t * HDIM;
  float4 v = *(const float4*)(xr + tid * 4);
  float ss = v.x*v.x + v.y*v.y + v.z*v.z + v.w*v.w;
  #pragma unroll
  for (int m = 32; m; m >>= 1) ss += __shfl_xor(ss, m);
  __shared__ float sb[4];
  if ((tid & 63) == 0) sb[tid >> 6] = ss;
  __syncthreads();
  ss = sb[0] + sb[1] + sb[2] + sb[3];
  float sc = 1.0f / sqrtf(ss * (1.f/HDIM) + RMS_EPS);
  float4 wv = *(const float4*)(w + tid * 4);
  float ov[4] = {v.x*sc*wv.x, v.y*sc*wv.y, v.z*sc*wv.z, v.w*sc*wv.w};
  short4v hv, lv;
  #pragma unroll
  for (int j = 0; j < 4; j++) { u16 h, l; split2(ov[j], h, l); hv[j]=(short)h; lv[j]=(short)l; }
  *(short4v*)&oh[(long)t*HDIM + tid*4] = hv;
  *(short4v*)&ol[(long)t*HDIM + tid*4] = lv;
}

// ---------------- RoPE cos/sin table (matches np f32 semantics) ----------------
__global__ __launch_bounds__(256)
void rope_table_kernel(float* __restrict__ tab) {
  int idx = blockIdx.x * 256 + threadIdx.x;   // SEQ*32
  int i = idx & 31, pos = idx >> 5;
  double e = -(double)i * 0.28782313662425575;   // ln(10000)/32
  float inv = (float)exp(e);
  float f = (float)pos * inv;
  tab[idx] = cosf(f);
  tab[SEQ*32 + idx] = sinf(f);
}

// =========== shared GEMM core: BM=256, BN=64, BK=32, 256 thr, 4 waves ==========
#define GPAD 40

#define GEMM_CORE(A_ROW_VALID)                                                 \
  f32x4 acc[4][4];                                                             \
  _Pragma("unroll") for (int m = 0; m < 4; m++)                                \
    _Pragma("unroll") for (int n = 0; n < 4; n++) acc[m][n] = {0.f,0.f,0.f,0.f};\
  int b_col = tid & 63;                                                        \
  int b_kh = (tid >> 6) * 8;                                                   \
  for (int k0 = 0; k0 < K; k0 += 32) {                                         \
    if (A_ROW_VALID) {                                                         \
      const u16* ah = Ah + arow * (long)K + k0;                                \
      const u16* al = Al + arow * (long)K + k0;                                \
      _Pragma("unroll") for (int q = 0; q < 4; q++) {                          \
        *(short8*)&As[0][tid][q*8] = *(const short8*)(ah + q*8);               \
        *(short8*)&As[1][tid][q*8] = *(const short8*)(al + q*8);               \
      }                                                                        \
    } else {                                                                   \
      short8 z = {0,0,0,0,0,0,0,0};                                            \
      _Pragma("unroll") for (int q = 0; q < 4; q++) {                          \
        *(short8*)&As[0][tid][q*8] = z; *(short8*)&As[1][tid][q*8] = z;        \
      }                                                                        \
    }                                                                          \
    {                                                                          \
      const float* bp = Bp + (long)(k0 + b_kh) * Nb + bcol0 + b_col;           \
      short8 hv, lv;                                                           \
      _Pragma("unroll") for (int j = 0; j < 8; j++) {                          \
        u16 h, l; split2(bp[(long)j * Nb], h, l);                              \
        hv[j] = (short)h; lv[j] = (short)l;                                    \
      }                                                                        \
      *(short8*)&Bs[0][b_col][b_kh] = hv;                                      \
      *(short8*)&Bs[1][b_col][b_kh] = lv;                                      \
    }                                                                          \
    __syncthreads();                                                           \
    short8 bf[2][4];                                                           \
    _Pragma("unroll") for (int t = 0; t < 2; t++)                              \
      _Pragma("unroll") for (int n = 0; n < 4; n++)                            \
        bf[t][n] = *(const short8*)&Bs[t][n*16 + lr][lg*8];                    \
    _Pragma("unroll") for (int m = 0; m < 4; m++) {                            \
      short8 afh = *(const short8*)&As[0][wr + m*16 + lr][lg*8];               \
      short8 afl = *(const short8*)&As[1][wr + m*16 + lr][lg*8];               \
      _Pragma("unroll") for (int n = 0; n < 4; n++) {                          \
        f32x4 a = acc[m][n];                                                   \
        a = __builtin_amdgcn_mfma_f32_16x16x32_bf16(afh, bf[0][n], a, 0, 0, 0);\
        a = __builtin_amdgcn_mfma_f32_16x16x32_bf16(afh, bf[1][n], a, 0, 0, 0);\
        a = __builtin_amdgcn_mfma_f32_16x16x32_bf16(afl, bf[0][n], a, 0, 0, 0);\
        acc[m][n] = a;                                                         \
      }                                                                        \
    }                                                                          \
    __syncthreads();                                                           \
  }

// MODE 0: Cf = acc ; MODE 2: Cf = clip(Cf+acc).  1D grid + XCD swizzle.
// if offs: per-expert grid chunk = gridDim.x/8 = nrow*ncol.
template<int MODE>
__global__ __launch_bounds__(256, 3)
void gemm_moe(const u16* __restrict__ Ah, const u16* __restrict__ Al,
              const float* __restrict__ B, float* __restrict__ Cf,
              const int* __restrict__ gather, const int* __restrict__ offs,
              int M, int N, int K, long bstride, int ncol)
{
  __shared__ u16 As[2][256][GPAD];
  __shared__ u16 Bs[2][64][GPAD];
  int nwg = gridDim.x;
  int bid = swz8(blockIdx.x, nwg);
  int z, rr2, rs, re;
  if (offs) {
    int cpe = nwg >> 3;
    z = bid / cpe; rr2 = bid % cpe;
    rs = offs[z]; re = offs[z + 1];
  } else { z = 0; rr2 = bid; rs = 0; re = M; }
  int brow = rr2 / ncol, bcol = rr2 % ncol;
  int p0 = rs + brow * 256;
  if (p0 >= re) return;
  int bcol0 = bcol * 64;
  const float* Bp = B + (long)z * bstride;
  int Nb = N;
  int tid = threadIdx.x, wv = tid >> 6, lane = tid & 63;
  int lr = lane & 15, lg = lane >> 4;
  int wr = wv * 64;
  long arow = -1;
  { int rr = p0 + tid; if (rr < re) arow = gather ? gather[rr] : rr; }
  GEMM_CORE(arow >= 0)
  #pragma unroll
  for (int m = 0; m < 4; m++) {
    int row0 = p0 + wr + m*16 + lg*4;
    #pragma unroll
    for (int n = 0; n < 4; n++) {
      int col = bcol0 + n*16 + lr;
      #pragma unroll
      for (int r = 0; r < 4; r++) {
        int row = row0 + r;
        if (row < re) {
          float vvv = acc[m][n][r];
          long idx = (long)row * N + col;
          if constexpr (MODE == 0) Cf[idx] = vvv;
          else Cf[idx] = clip100(Cf[idx] + vvv);
        }
      }
    }
  }
}

// ---------- fused MoE gate+up GEMM: h = silu(x@wg) * (x@wu), pre-split out ----------
__global__ __launch_bounds__(256, 2)
void gemm_gateup(const u16* __restrict__ Ah, const u16* __restrict__ Al,
                 const float* __restrict__ Bg, const float* __restrict__ Bu,
                 u16* __restrict__ Ch, u16* __restrict__ Cl,
                 const int* __restrict__ gather, const int* __restrict__ offs)
{
  __shared__ u16 As[2][256][GPAD];
  __shared__ u16 Bgs[2][64][GPAD];
  __shared__ u16 Bus[2][64][GPAD];
  const int K = HDIM, N = FFDIM;
  int nwg = gridDim.x;                    // 8192 = 8 exp * 32 row * 32 col
  int bid = swz8(blockIdx.x, nwg);
  int cpe = nwg >> 3;                     // 1024 per expert
  int z = bid / cpe, rr2 = bid % cpe;
  int rs = offs[z], re = offs[z + 1];
  int brow = rr2 >> 5, bcol = rr2 & 31;
  int p0 = rs + brow * 256;
  if (p0 >= re) return;
  int bcol0 = bcol * 64;
  const float* Bpg = Bg + (long)z * ((long)HDIM * FFDIM);
  const float* Bpu = Bu + (long)z * ((long)HDIM * FFDIM);
  int tid = threadIdx.x, wv = tid >> 6, lane = tid & 63;
  int lr = lane & 15, lg = lane >> 4;
  int wr = wv * 64;
  long arow = -1;
  { int rr = p0 + tid; if (rr < re) arow = gather[rr]; }
  f32x4 accg[4][4], accu[4][4];
  #pragma unroll
  for (int m = 0; m < 4; m++)
    #pragma unroll
    for (int n = 0; n < 4; n++) { accg[m][n] = {0.f,0.f,0.f,0.f}; accu[m][n] = {0.f,0.f,0.f,0.f}; }
  int b_col = tid & 63;
  int b_kh = (tid >> 6) * 8;
  for (int k0 = 0; k0 < K; k0 += 32) {
    if (arow >= 0) {
      const u16* ah = Ah + arow * (long)K + k0;
      const u16* al = Al + arow * (long)K + k0;
      #pragma unroll
      for (int q = 0; q < 4; q++) {
        *(short8*)&As[0][tid][q*8] = *(const short8*)(ah + q*8);
        *(short8*)&As[1][tid][q*8] = *(const short8*)(al + q*8);
      }
    } else {
      short8 zz = {0,0,0,0,0,0,0,0};
      #pragma unroll
      for (int q = 0; q < 4; q++) { *(short8*)&As[0][tid][q*8] = zz; *(short8*)&As[1][tid][q*8] = zz; }
    }
    {
      const float* bpg = Bpg + (long)(k0 + b_kh) * N + bcol0 + b_col;
      const float* bpu = Bpu + (long)(k0 + b_kh) * N + bcol0 + b_col;
      short8 ghv, glv, uhv, ulv;
      #pragma unroll
      for (int j = 0; j < 8; j++) {
        u16 h, l;
        split2(bpg[(long)j * N], h, l); ghv[j] = (short)h; glv[j] = (short)l;
        split2(bpu[(long)j * N], h, l); uhv[j] = (short)h; ulv[j] = (short)l;
      }
      *(short8*)&Bgs[0][b_col][b_kh] = ghv;
      *(short8*)&Bgs[1][b_col][b_kh] = glv;
      *(short8*)&Bus[0][b_col][b_kh] = uhv;
      *(short8*)&Bus[1][b_col][b_kh] = ulv;
    }
    __syncthreads();
    short8 afh[4], afl[4];
    #pragma unroll
    for (int m = 0; m < 4; m++) {
      afh[m] = *(const short8*)&As[0][wr + m*16 + lr][lg*8];
      afl[m] = *(const short8*)&As[1][wr + m*16 + lr][lg*8];
    }
    #pragma unroll
    for (int n = 0; n < 4; n++) {
      short8 bgh = *(const short8*)&Bgs[0][n*16 + lr][lg*8];
      short8 bgl = *(const short8*)&Bgs[1][n*16 + lr][lg*8];
      short8 buh = *(const short8*)&Bus[0][n*16 + lr][lg*8];
      short8 bul = *(const short8*)&Bus[1][n*16 + lr][lg*8];
      #pragma unroll
      for (int m = 0; m < 4; m++) {
        f32x4 g = accg[m][n];
        g = __builtin_amdgcn_mfma_f32_16x16x32_bf16(afh[m], bgh, g, 0, 0, 0);
        g = __builtin_amdgcn_mfma_f32_16x16x32_bf16(afh[m], bgl, g, 0, 0, 0);
        g = __builtin_amdgcn_mfma_f32_16x16x32_bf16(afl[m], bgh, g, 0, 0, 0);
        accg[m][n] = g;
        f32x4 u = accu[m][n];
        u = __builtin_amdgcn_mfma_f32_16x16x32_bf16(afh[m], buh, u, 0, 0, 0);
        u = __builtin_amdgcn_mfma_f32_16x16x32_bf16(afh[m], bul, u, 0, 0, 0);
        u = __builtin_amdgcn_mfma_f32_16x16x32_bf16(afl[m], buh, u, 0, 0, 0);
        accu[m][n] = u;
      }
    }
    __syncthreads();
  }
  #pragma unroll
  for (int m = 0; m < 4; m++) {
    int row0 = p0 + wr + m*16 + lg*4;
    #pragma unroll
    for (int n = 0; n < 4; n++) {
      int col = bcol0 + n*16 + lr;
      #pragma unroll
      for (int r = 0; r < 4; r++) {
        int row = row0 + r;
        if (row < re) {
          float gv = accg[m][n][r], uv = accu[m][n][r];
          float hh = gv / (1.f + __expf(-gv)) * uv;
          u16 h, l; split2(hh, h, l);
          long idx = (long)row * N + col;
          Ch[idx] = h; Cl[idx] = l;
        }
      }
    }
  }
}

// fused QKV GEMM: 1D grid 384 (bx 0..23 fast, 16 row panels), XCD swizzled
__global__ __launch_bounds__(256, 3)
void gemm_qkv(const u16* __restrict__ Ah, const u16* __restrict__ Al,
              const float* __restrict__ wq, const float* __restrict__ wk,
              const float* __restrict__ wv_, const float* __restrict__ tab,
              u16* __restrict__ qh, u16* __restrict__ ql,
              u16* __restrict__ kh_, u16* __restrict__ kl_,
              u16* __restrict__ vth, u16* __restrict__ vtl)
{
  __shared__ u16 As[2][256][GPAD];
  __shared__ u16 Bs[2][64][GPAD];
  int bid = swz8(blockIdx.x, gridDim.x);
  int bx = bid % 24;
  int p0 = (bid / 24) * 256;
  const float* Bp; int Nb, bcol0;
  if (bx < 16)      { Bp = wq;  Nb = 1024; bcol0 = bx * 64; }
  else if (bx < 20) { Bp = wk;  Nb = 256;  bcol0 = (bx - 16) * 64; }
  else              { Bp = wv_; Nb = 256;  bcol0 = (bx - 20) * 64; }
  int K = HDIM;
  int tid = threadIdx.x, wv = tid >> 6, lane = tid & 63;
  int lr = lane & 15, lg = lane >> 4;
  int wr = wv * 64;
  long arow = p0 + tid;
  GEMM_CORE(true)
  if (bx < 16) {          // ---- q: rope + split ----
    int h = bx;
    #pragma unroll
    for (int m = 0; m < 4; m++) {
      #pragma unroll
      for (int r = 0; r < 4; r++) {
        int tok = p0 + wr + m*16 + lg*4 + r;
        int pos = tok & (SEQ - 1);
        #pragma unroll
        for (int n = 0; n < 2; n++) {
          int i = n*16 + lr;
          float c = tab[pos*32 + i], s = tab[SEQ*32 + pos*32 + i];
          float x0 = acc[m][n][r], x1 = acc[m][n+2][r];
          float y0 = x0*c - x1*s, y1 = x1*c + x0*s;
          long base = (long)tok*1024 + h*64 + i;
          u16 h0, l0; split2(y0, h0, l0); qh[base] = h0; ql[base] = l0;
          u16 h1, l1; split2(y1, h1, l1); qh[base+32] = h1; ql[base+32] = l1;
        }
      }
    }
  } else if (bx < 20) {   // ---- k: rope + split ----
    int kvh = bx - 16;
    #pragma unroll
    for (int m = 0; m < 4; m++) {
      #pragma unroll
      for (int r = 0; r < 4; r++) {
        int tok = p0 + wr + m*16 + lg*4 + r;
        int pos = tok & (SEQ - 1);
        #pragma unroll
        for (int n = 0; n < 2; n++) {
          int i = n*16 + lr;
          float c = tab[pos*32 + i], s = tab[SEQ*32 + pos*32 + i];
          float x0 = acc[m][n][r], x1 = acc[m][n+2][r];
          float y0 = x0*c - x1*s, y1 = x1*c + x0*s;
          long base = (long)tok*256 + kvh*64 + i;
          u16 h0, l0; split2(y0, h0, l0); kh_[base] = h0; kl_[base] = l0;
          u16 h1, l1; split2(y1, h1, l1); kh_[base+32] = h1; kl_[base+32] = l1;
        }
      }
    }
  } else {                // ---- v: split + transpose ----
    int kvh = bx - 20;
    #pragma unroll
    for (int m = 0; m < 4; m++) {
      #pragma unroll
      for (int r = 0; r < 4; r++) {
        int tok = p0 + wr + m*16 + lg*4 + r;
        int bb = tok >> 11, tl = tok & (SEQ - 1);
        #pragma unroll
        for (int n = 0; n < 4; n++) {
          int hd = n*16 + lr;
          u16 h0, l0; split2(acc[m][n][r], h0, l0);
          long vidx = ((long)(bb*NKVH + kvh)*64 + hd)*SEQ + tl;
          vth[vidx] = h0; vtl[vidx] = l0;
        }
      }
    }
  }
}

// ---------------- causal flash attention, pre-split inputs ----------------
#define ATP 72
__global__ __launch_bounds__(256)
void attn_kernel(const u16* __restrict__ qhi, const u16* __restrict__ qlo,
                 const u16* __restrict__ khi, const u16* __restrict__ klo,
                 const u16* __restrict__ vthi, const u16* __restrict__ vtlo,
                 u16* __restrict__ ohi, u16* __restrict__ olo)
{
  int bid = swz8(blockIdx.x, gridDim.x);   // chunk 64 = one (b, kvh) group
  int qp = bid & 15, h = (bid >> 4) & 15, b = bid >> 8;
  int kvh = h >> 2;
  int tid = threadIdx.x, w = tid >> 6, lane = tid & 63;
  int lr = lane & 15, lg = lane >> 4;
  __shared__ u16 KhS[64][ATP], KlS[64][ATP], VhS[64][ATP], VlS[64][ATP];
  __shared__ u16 Ps[2][4][16][ATP];
  long tokbase = (long)b * SEQ;
  int sr = tid >> 2, scg = (tid & 3) * 16;
  const u16* vrow_h = vthi + ((long)(b*NKVH + kvh)*64 + sr)*SEQ;
  const u16* vrow_l = vtlo + ((long)(b*NKVH + kvh)*64 + sr)*SEQ;

  for (int ph = 0; ph < 2; ph++) {
    int qt = ph ? (31 - qp) : qp;
    long q0 = (long)qt * 64;
    const u16* qh_row = qhi + (tokbase + q0 + w*16 + lr)*1024 + h*64;
    const u16* ql_row = qlo + (tokbase + q0 + w*16 + lr)*1024 + h*64;
    short8 aqh[2], aql[2];
    #pragma unroll
    for (int hf = 0; hf < 2; hf++) {
      aqh[hf] = *(const short8*)(qh_row + hf*32 + lg*8);
      aql[hf] = *(const short8*)(ql_row + hf*32 + lg*8);
    }
    f32x4 Oacc[4];
    #pragma unroll
    for (int n = 0; n < 4; n++) Oacc[n] = {0.f,0.f,0.f,0.f};
    float mrow[4] = {-1e30f,-1e30f,-1e30f,-1e30f};
    float lrow[4] = {0.f,0.f,0.f,0.f};
    for (int kt = 0; kt <= qt; kt++) {
      if (ph | kt) __syncthreads();
      {
        long kg = (tokbase + kt*64 + sr)*256 + kvh*64 + scg;
        *(short8*)&KhS[sr][scg]   = *(const short8*)(khi + kg);
        *(short8*)&KhS[sr][scg+8] = *(const short8*)(khi + kg + 8);
        *(short8*)&KlS[sr][scg]   = *(const short8*)(klo + kg);
        *(short8*)&KlS[sr][scg+8] = *(const short8*)(klo + kg + 8);
        long vg = kt*64 + scg;
        *(short8*)&VhS[sr][scg]   = *(const short8*)(vrow_h + vg);
        *(short8*)&VhS[sr][scg+8] = *(const short8*)(vrow_h + vg + 8);
        *(short8*)&VlS[sr][scg]   = *(const short8*)(vrow_l + vg);
        *(short8*)&VlS[sr][scg+8] = *(const short8*)(vrow_l + vg + 8);
      }
      __syncthreads();
      float sv[4][4];
      #pragma unroll
      for (int n = 0; n < 4; n++) {
        short8 bh0 = *(const short8*)&KhS[n*16 + lr][lg*8];
        short8 bh1 = *(const short8*)&KhS[n*16 + lr][32 + lg*8];
        short8 bl0 = *(const short8*)&KlS[n*16 + lr][lg*8];
        short8 bl1 = *(const short8*)&KlS[n*16 + lr][32 + lg*8];
        f32x4 c = {0.f,0.f,0.f,0.f};
        c = __builtin_amdgcn_mfma_f32_16x16x32_bf16(aqh[0], bh0, c, 0, 0, 0);
        c = __builtin_amdgcn_mfma_f32_16x16x32_bf16(aqh[1], bh1, c, 0, 0, 0);
        c = __builtin_amdgcn_mfma_f32_16x16x32_bf16(aqh[0], bl0, c, 0, 0, 0);
        c = __builtin_amdgcn_mfma_f32_16x16x32_bf16(aqh[1], bl1, c, 0, 0, 0);
        c = __builtin_amdgcn_mfma_f32_16x16x32_bf16(aql[0], bh0, c, 0, 0, 0);
        c = __builtin_amdgcn_mfma_f32_16x16x32_bf16(aql[1], bh1, c, 0, 0, 0);
        #pragma unroll
        for (int r = 0; r < 4; r++) sv[n][r] = c[r] * 0.125f;
      }
      if (kt == qt) {
        #pragma unroll
        for (int n = 0; n < 4; n++)
          #pragma unroll
          for (int r = 0; r < 4; r++)
            if (n*16 + lr > w*16 + lg*4 + r) sv[n][r] = -1e30f;
      }
      float pvv[4][4], alpha[4];
      #pragma unroll
      for (int r = 0; r < 4; r++) {
        float vm = fmaxf(fmaxf(sv[0][r], sv[1][r]), fmaxf(sv[2][r], sv[3][r]));
        #pragma unroll
        for (int msk = 1; msk < 16; msk <<= 1) vm = fmaxf(vm, __shfl_xor(vm, msk));
        float mnew = fmaxf(mrow[r], vm);
        alpha[r] = __expf(mrow[r] - mnew);
        float psum = 0.f;
        #pragma unroll
        for (int n = 0; n < 4; n++) { pvv[n][r] = __expf(sv[n][r] - mnew); psum += pvv[n][r]; }
        #pragma unroll
        for (int msk = 1; msk < 16; msk <<= 1) psum += __shfl_xor(psum, msk);
        lrow[r] = lrow[r] * alpha[r] + psum;
        mrow[r] = mnew;
      }
      #pragma unroll
      for (int n = 0; n < 4; n++)
        #pragma unroll
        for (int r = 0; r < 4; r++) {
          u16 t0, t1;
          split2(pvv[n][r], t0, t1);
          Ps[0][w][lg*4 + r][n*16 + lr] = t0;
          Ps[1][w][lg*4 + r][n*16 + lr] = t1;
        }
      #pragma unroll
      for (int n = 0; n < 4; n++)
        #pragma unroll
        for (int r = 0; r < 4; r++) Oacc[n][r] *= alpha[r];
      #pragma unroll
      for (int kk = 0; kk < 2; kk++) {
        short8 aph = *(const short8*)&Ps[0][w][lr][kk*32 + lg*8];
        short8 apl = *(const short8*)&Ps[1][w][lr][kk*32 + lg*8];
        #pragma unroll
        for (int n = 0; n < 4; n++) {
          short8 bvh = *(const short8*)&VhS[n*16 + lr][kk*32 + lg*8];
          short8 bvl = *(const short8*)&VlS[n*16 + lr][kk*32 + lg*8];
          f32x4 a = Oacc[n];
          a = __builtin_amdgcn_mfma_f32_16x16x32_bf16(aph, bvh, a, 0, 0, 0);
          a = __builtin_amdgcn_mfma_f32_16x16x32_bf16(aph, bvl, a, 0, 0, 0);
          a = __builtin_amdgcn_mfma_f32_16x16x32_bf16(apl, bvh, a, 0, 0, 0);
          Oacc[n] = a;
        }
      }
    }
    u16* oh_row = ohi + (tokbase + q0 + w*16)*1024 + h*64;
    u16* ol_row = olo + (tokbase + q0 + w*16)*1024 + h*64;
    #pragma unroll
    for (int n = 0; n < 4; n++)
      #pragma unroll
      for (int r = 0; r < 4; r++) {
        float v = Oacc[n][r] / lrow[r];
        u16 h0, l0; split2(v, h0, l0);
        oh_row[(lg*4 + r)*1024 + n*16 + lr] = h0;
        ol_row[(lg*4 + r)*1024 + n*16 + lr] = l0;
      }
  }
}

// ---------------- router (pure fp32) ----------------
__global__ __launch_bounds__(64)
void router_kernel(const float* __restrict__ x, const float* __restrict__ w2,
                   const float* __restrict__ wr, int* __restrict__ tok_e,
                   float* __restrict__ tok_w, int* __restrict__ counts)
{
  int t = blockIdx.x, l = threadIdx.x;
  const float* xr = x + (long)t * HDIM;
  float xv[16];
  float ss = 0.f;
  #pragma unroll
  for (int j = 0; j < 16; j++) { xv[j] = xr[l + j*64]; ss += xv[j]*xv[j]; }
  #pragma unroll
  for (int m = 32; m; m >>= 1) ss += __shfl_xor(ss, m);
  float sc = 1.0f / sqrtf(ss * (1.f/HDIM) + RMS_EPS);
  float acc[8] = {0,0,0,0,0,0,0,0};
  #pragma unroll
  for (int j = 0; j < 16; j++) {
    int hh = l + j*64;
    float xnv = xv[j] * sc * w2[hh];
    const float* wrow = wr + hh * 8;
    #pragma unroll
    for (int e = 0; e < 8; e++) acc[e] += xnv * wrow[e];
  }
  #pragma unroll
  for (int e = 0; e < 8; e++)
    #pragma unroll
    for (int m = 32; m; m >>= 1) acc[e] += __shfl_xor(acc[e], m);
  if (l == 0) {
    float mx = acc[0];
    #pragma unroll
    for (int e = 1; e < 8; e++) mx = fmaxf(mx, acc[e]);
    float ex[8], s = 0.f;
    #pragma unroll
    for (int e = 0; e < 8; e++) { ex[e] = expf(acc[e] - mx); s += ex[e]; }
    int e0 = 0;
    #pragma unroll
    for (int e = 1; e < 8; e++) if (ex[e] > ex[e0]) e0 = e;
    int e1 = (e0 == 0) ? 1 : 0;
    for (int e = 0; e < 8; e++) if (e != e0 && ex[e] > ex[e1]) e1 = e;
    float v0 = ex[e0] / s, v1 = ex[e1] / s, wsum = v0 + v1;
    tok_e[2*t] = e0; tok_e[2*t+1] = e1;
    tok_w[2*t] = v0 / wsum; tok_w[2*t+1] = v1 / wsum;
    atomicAdd(&counts[e0], 1);
    atomicAdd(&counts[e1], 1);
  }
}

__global__ void scan_kernel(const int* __restrict__ counts, int* __restrict__ offs,
                            int* __restrict__ cursor) {
  if (threadIdx.x == 0 && blockIdx.x == 0) {
    int s = 0;
    for (int e = 0; e < NEXP; e++) { offs[e] = s; cursor[e] = s; s += counts[e]; }
    offs[NEXP] = s;
  }
}

__global__ __launch_bounds__(256)
void scatter_kernel(const int* __restrict__ tok_e, int* __restrict__ cursor,
                    int* __restrict__ tok_of_pair, int* __restrict__ tok_slot) {
  int t = blockIdx.x * 256 + threadIdx.x;
  if (t >= NTOK) return;
  #pragma unroll
  for (int s = 0; s < 2; s++) {
    int e = tok_e[2*t + s];
    int pos = atomicAdd(&cursor[e], 1);
    tok_of_pair[pos] = t;
    tok_slot[2*t + s] = pos;
  }
}

// x = clip(x + w0*po[s0] + w1*po[s1])
__global__ __launch_bounds__(256)
void combine_kernel(float* __restrict__ x, const float* __restrict__ po,
                    const int* __restrict__ tok_slot, const float* __restrict__ tok_w) {
  int t = blockIdx.x, tid = threadIdx.x;
  long s0 = tok_slot[2*t], s1 = tok_slot[2*t+1];
  float w0 = tok_w[2*t], w1 = tok_w[2*t+1];
  int c = tid * 4;
  float4 xv = *(float4*)(x + (long)t*HDIM + c);
  float4 a  = *(const float4*)(po + s0*HDIM + c);
  float4 bb = *(const float4*)(po + s1*HDIM + c);
  xv.x = clip100(xv.x + w0*a.x + w1*bb.x);
  xv.y = clip100(xv.y + w0*a.y + w1*bb.y);
  xv.z = clip100(xv.z + w0*a.z + w1*bb.z);
  xv.w = clip100(xv.w + w0*a.w + w1*bb.w);
  *(float4*)(x + (long)t*HDIM + c) = xv;
}

extern "C" void kernel_launch(void* const* d_in, const int* in_sizes, int n_in,
                              void* d_out, int out_size, void* d_ws, size_t ws_size,
                              hipStream_t stream)
{
  (void)in_sizes; (void)n_in; (void)out_size; (void)ws_size;
  const float* hs  = (const float*)d_in[0];
  const float* ln1 = (const float*)d_in[1];
  const float* ln2 = (const float*)d_in[2];
  const float* wq  = (const float*)d_in[3];
  const float* wk  = (const float*)d_in[4];
  const float* wvv = (const float*)d_in[5];
  const float* wo  = (const float*)d_in[6];
  const float* wr  = (const float*)d_in[7];
  const float* wg  = (const float*)d_in[8];
  const float* wu  = (const float*)d_in[9];
  const float* wd  = (const float*)d_in[10];
  float* x = (float*)d_out;

  char* p = (char*)d_ws;
  auto carve = [&](size_t bytes) {
    char* r = p; p += (bytes + 255) & ~(size_t)255; return r;
  };
  float* tab = (float*)carve((size_t)SEQ * 32 * 2 * 4);
  u16* xnh = (u16*)carve((size_t)NTOK * HDIM * 2);
  u16* xnl = (u16*)carve((size_t)NTOK * HDIM * 2);
  char* R  = carve((size_t)128 * 1024 * 1024);   // shared attn / MoE region
  // attn phase layout
  u16* qhi = (u16*)R;                              // 8MB
  u16* qlo = (u16*)(R + 8u*1024*1024);             // 8MB
  u16* khi = (u16*)(R + 16u*1024*1024);            // 2MB
  u16* klo = (u16*)(R + 18u*1024*1024);            // 2MB
  u16* vthi= (u16*)(R + 20u*1024*1024);            // 2MB
  u16* vtlo= (u16*)(R + 22u*1024*1024);            // 2MB
  u16* ohi = (u16*)(R + 24u*1024*1024);            // 8MB
  u16* olo = (u16*)(R + 32u*1024*1024);            // 8MB
  // MoE phase layout (aliases attn; sequential stream order makes this safe)
  u16*   ghi = (u16*)R;                            // 32MB
  u16*   glo = (u16*)(R + 32u*1024*1024);          // 32MB
  float* po  = (float*)(R + 64u*1024*1024);        // 32MB
  int*   tok_e       = (int*)carve(NTOK * 2 * 4);
  float* tok_w       = (float*)carve(NTOK * 2 * 4);
  int*   tok_slot    = (int*)carve(NTOK * 2 * 4);
  int*   tok_of_pair = (int*)carve(NPAIR * 4);
  int*   counts      = (int*)carve(8 * 4);
  int*   offs        = (int*)carve(9 * 4);
  int*   cursor      = (int*)carve(8 * 4);

  hipMemcpyAsync(x, hs, (size_t)NTOK * HDIM * 4, hipMemcpyDeviceToDevice, stream);
  rope_table_kernel<<<SEQ*32/256, 256, 0, stream>>>(tab);

  for (int l = 0; l < NLAYER; l++) {
    rmsnorm_kernel<<<NTOK, 256, 0, stream>>>(x, ln1 + (long)l*HDIM, xnh, xnl);
    gemm_qkv<<<384, 256, 0, stream>>>(
        xnh, xnl, wq + (long)l*HDIM*1024, wk + (long)l*HDIM*256,
        wvv + (long)l*HDIM*256, tab, qhi, qlo, khi, klo, vthi, vtlo);
    attn_kernel<<<512, 256, 0, stream>>>(
        qhi, qlo, khi, klo, vthi, vtlo, ohi, olo);
    gemm_moe<2><<<256, 256, 0, stream>>>(
        ohi, olo, wo + (long)l*1024*HDIM, x,
        nullptr, nullptr, NTOK, HDIM, 1024, 0, 16);

    rmsnorm_kernel<<<NTOK, 256, 0, stream>>>(x, ln2 + (long)l*HDIM, xnh, xnl);
    hipMemsetAsync(counts, 0, 8 * 4, stream);
    router_kernel<<<NTOK, 64, 0, stream>>>(
        x, ln2 + (long)l*HDIM, wr + (long)l*HDIM*NEXP, tok_e, tok_w, counts);
    scan_kernel<<<1, 64, 0, stream>>>(counts, offs, cursor);
    scatter_kernel<<<NTOK/256, 256, 0, stream>>>(tok_e, cursor, tok_of_pair, tok_slot);
    gemm_gateup<<<8192, 256, 0, stream>>>(
        xnh, xnl, wg + (long)l*NEXP*HDIM*FFDIM, wu + (long)l*NEXP*HDIM*FFDIM,
        ghi, glo, tok_of_pair, offs);
    gemm_moe<0><<<4096, 256, 0, stream>>>(
        ghi, glo, wd + (long)l*NEXP*FFDIM*HDIM, po,
        nullptr, offs, 0, HDIM, FFDIM, (long)FFDIM*HDIM, 16);
    combine_kernel<<<NTOK, 256, 0, stream>>>(x, po, tok_slot, tok_w);
  }
}